// Round 11
// baseline (744.680 us; speedup 1.0000x reference)
//
#include <hip/hip_runtime.h>
#include <stdint.h>

#define NU 100000
#define NI 50000
#define NBK 10
#define DD 64
#define NE 1000000
#define BATCH 2048
#define NSLICE 8
#define USLICE ((NU + NSLICE - 1) / NSLICE)   // 12500
#define ISLICE ((NI + NSLICE - 1) / NSLICE)   // 6250
#define NCHUNK 512
#define EPC ((NE + NCHUNK - 1) / NCHUNK)      // 1954
// row bucket capacities: degrees are Poisson(10) U / Poisson(20) I;
// P(any row exceeds) < 1e-5 overall, +64-entry allocation slack.
#define CAP_U 36
#define CAP_I 56
// fp8 storage scale: embeddings ~0.01 are subnormal in e4m3; x128 -> normal.
// Combined descale: (4/3 dropout) / 128 = 1/96.
#define FP8_SCALE 128.0f
#define SPMM_DESCALE (1.0f / 96.0f)
#define EL_DESCALE (1.0f / 16384.0f)   // edge-logit dot of two 128x fp8 tables
#define LOG2E5 7.2134752f              // 5*log2(e): exp(5x) = 2^(x*LOG2E5)
// av in [0, 0.05): 11-bit fixed point in cp bits 21..31 (cp entry = ONE int:
// col 17b | mask 4b @17 | av 11b @21).
#define AV_ENC 40960.0f                // 2^11 / 0.05
#define AV_DEC (0.05f / 2048.0f)
// aug weights stored u16 fixed-point (rel err ~2e-5, << fp8 table error)
#define AUG_ENC (65535.0f / 0.05f)
#define AUG_DEC (0.05f / 65535.0f)

typedef __bf16 bf16x8 __attribute__((ext_vector_type(8)));
typedef float f32x4 __attribute__((ext_vector_type(4)));
typedef float f32x2 __attribute__((ext_vector_type(2)));

struct Keys8 { uint32_t k[8][2]; };

// ---------------- threefry2x32 (JAX-compatible, 20 rounds) ----------------
__host__ __device__ inline void tf2x32(uint32_t k0, uint32_t k1, uint32_t x0, uint32_t x1,
                                       uint32_t& o0, uint32_t& o1) {
  uint32_t ks0 = k0, ks1 = k1, ks2 = k0 ^ k1 ^ 0x1BD11BDAu;
  x0 += ks0; x1 += ks1;
#define TFR(r) { x0 += x1; x1 = (x1 << (r)) | (x1 >> (32 - (r))); x1 ^= x0; }
  TFR(13) TFR(15) TFR(26) TFR(6)   x0 += ks1; x1 += ks2 + 1u;
  TFR(17) TFR(29) TFR(16) TFR(24)  x0 += ks2; x1 += ks0 + 2u;
  TFR(13) TFR(15) TFR(26) TFR(6)   x0 += ks0; x1 += ks1 + 3u;
  TFR(17) TFR(29) TFR(16) TFR(24)  x0 += ks1; x1 += ks2 + 4u;
  TFR(13) TFR(15) TFR(26) TFR(6)   x0 += ks2; x1 += ks0 + 5u;
#undef TFR
  o0 = x0; o1 = x1;
}

__device__ inline uint16_t f2bf(float f) {
  uint32_t u = __float_as_uint(f);
  return (uint16_t)((u + 0x7fffu + ((u >> 16) & 1u)) >> 16);   // RNE
}
__device__ inline float bf2f(uint16_t u) {
  return __uint_as_float(((uint32_t)u) << 16);
}

// ---- fp8 e4m3 (OCP) helpers ----
template <int SEL>
__device__ inline float fp8_sel(uint32_t w) {
#if __has_builtin(__builtin_amdgcn_cvt_f32_fp8)
  return __builtin_amdgcn_cvt_f32_fp8((int)w, SEL);
#else
  uint32_t b = (w >> (8 * SEL)) & 0xFFu;
  uint32_t s = b >> 7, e = (b >> 3) & 0xF, m = b & 7;
  float v = (e == 0) ? (float)m * (1.0f / 512.0f)
                     : __uint_as_float(((e + 120) << 23) | (m << 20));
  return s ? -v : v;
#endif
}
// packed decode: one dword of 4 fp8 -> f32x4 via 2x v_cvt_pk_f32_fp8
__device__ inline f32x4 fp8_to4(uint32_t w) {
#if __has_builtin(__builtin_amdgcn_cvt_pk_f32_fp8)
  f32x2 lo = __builtin_amdgcn_cvt_pk_f32_fp8((int)w, false);
  f32x2 hi = __builtin_amdgcn_cvt_pk_f32_fp8((int)w, true);
  f32x4 r; r[0] = lo[0]; r[1] = lo[1]; r[2] = hi[0]; r[3] = hi[1];
  return r;
#else
  f32x4 r; r[0] = fp8_sel<0>(w); r[1] = fp8_sel<1>(w);
  r[2] = fp8_sel<2>(w); r[3] = fp8_sel<3>(w);
  return r;
#endif
}
__device__ inline uint32_t f32_to_fp8(float f) {
#if __has_builtin(__builtin_amdgcn_cvt_pk_fp8_f32)
  return (uint32_t)__builtin_amdgcn_cvt_pk_fp8_f32(f, f, 0, false) & 0xFFu;
#else
  uint32_t s = (__float_as_uint(f) >> 31) << 7;
  float a = fabsf(f);
  a = fminf(a, 448.0f);
  if (a < 0.015625f) {
    uint32_t m = (uint32_t)(a * 512.0f + 0.5f);
    return s | m;
  }
  int ex; float fr = frexpf(a, &ex);
  uint32_t q = (uint32_t)(fr * 16.0f + 0.5f);
  int E = ex + 6;
  if (q == 16) { q = 8; E += 1; }
  if (E > 15) { E = 15; q = 14; }
  if (E == 15 && q == 15) q = 14;
  return s | ((uint32_t)E << 3) | (q - 8);
#endif
}
__device__ inline uint32_t pack4_fp8(float a, float b, float c, float d) {
  return f32_to_fp8(a) | (f32_to_fp8(b) << 8) | (f32_to_fp8(c) << 16) | (f32_to_fp8(d) << 24);
}

// dropout masks for edge pair (e, e+half) from ONE threefry eval per key:
// o0 -> element e, o1 -> element e+half (JAX split-iota semantics).
__global__ void mask_kernel(uint8_t* __restrict__ mask, Keys8 K) {
  const int half = NE / 2;
  int e = blockIdx.x * blockDim.x + threadIdx.x;
  if (e >= half) return;
  uint32_t mlo = 0, mhi = 0;
#pragma unroll
  for (int j = 0; j < 8; ++j) {
    uint32_t o0, o1;
    tf2x32(K.k[j][0], K.k[j][1], (uint32_t)e, (uint32_t)(e + half), o0, o1);
    float u0 = __uint_as_float((o0 >> 9) | 0x3f800000u) - 1.0f;
    float u1 = __uint_as_float((o1 >> 9) | 0x3f800000u) - 1.0f;
    mlo |= (u0 < 0.75f ? 1u : 0u) << j;
    mhi |= (u1 < 0.75f ? 1u : 0u) << j;
  }
  mask[e] = (uint8_t)mlo;
  mask[e + half] = (uint8_t)mhi;
}

// XCD-sliced bucket scatter (slice = blockIdx&7; L2-local atomics per round-2
// measurement). Fixed-capacity ROW BUCKETS self-allocated by atomicAdd.
// ~90-104us across 6 structural variants -> atomic/latency floor; left as-is.
__global__ __launch_bounds__(256)
void scatter_kernel(const int* __restrict__ rows, const int* __restrict__ cols,
                    const uint8_t* __restrict__ mask, const float* __restrict__ av,
                    int* __restrict__ cntU, int* __restrict__ cntI,
                    int* __restrict__ cpU, int* __restrict__ cpI) {
  int slice = blockIdx.x & 7;
  int chunk = blockIdx.x >> 3;
  int base = chunk * EPC;
  int end = base + EPC; if (end > NE) end = NE;
  for (int e = base + threadIdx.x; e < end; e += 256) {
    int r = __builtin_nontemporal_load(rows + e);
    int c = __builtin_nontemporal_load(cols + e);
    uint32_t m = __builtin_nontemporal_load(mask + e);
    float a = __builtin_nontemporal_load(av + e);
    uint32_t q = (uint32_t)(a * AV_ENC + 0.5f);
    if (q > 2047u) q = 2047u;
    uint32_t qb = q << 21;
    if (r / USLICE == slice) {
      int old = atomicAdd(&cntU[r], 1);
      cpU[r * CAP_U + old] = (int)((uint32_t)c | ((m & 0xFu) << 17) | qb);
    }
    if (c / ISLICE == slice) {
      int old = atomicAdd(&cntI[c], 1);
      cpI[c * CAP_I + old] = (int)((uint32_t)r | (((m >> 4) & 0xFu) << 17) | qb);
    }
  }
}

// weight: rdw!=null -> sequential u16 aug stream (prop1-L1); else decode the
// 11-bit packed av (prop0, no memory access).
__device__ inline float cp_weight(int cc, const uint16_t* __restrict__ rdw, int p, int shift) {
  float mb = (float)((cc >> shift) & 1);
  if (rdw) return (float)rdw[p] * AUG_DEC * mb;
  return (float)(((uint32_t)cc) >> 21) * AV_DEC * mb;
}

// merged U+I gather-reduce SpMM, sub-wave layout: wave = 4 rows x 16 lanes,
// lane covers 4 dims via one dword fp8 load. Zero-weight entries redirect
// their gather to row 0 (branchless; row 0 becomes L1/L2-hot).
__global__ __launch_bounds__(256)
void spmm_layer_kernel(const int* __restrict__ cntU, const int* __restrict__ cpU,
                       const int* __restrict__ cntI, const int* __restrict__ cpI,
                       const uint16_t* __restrict__ rdU, const uint16_t* __restrict__ rdI,
                       int shift,
                       const uint8_t* __restrict__ SU, const uint8_t* __restrict__ SI,
                       uint8_t* __restrict__ dU, uint8_t* __restrict__ dI,
                       uint16_t* __restrict__ sumU, uint16_t* __restrict__ sumI,
                       const float* __restrict__ baseU, const float* __restrict__ baseI,
                       uint8_t* __restrict__ s8U, uint8_t* __restrict__ s8I) {
  int lane = threadIdx.x & 63;
  int g = lane >> 4, l15 = lane & 15;
  int w = (blockIdx.x * blockDim.x + threadIdx.x) >> 6;
  int r = w * 4 + g;                       // NU%4==0 -> wave never straddles U/I
  const int* cnt; const int* cp; const uint8_t* S; const uint16_t* rdw;
  uint8_t* D; uint16_t* Sum; const float* base; uint8_t* S8; int row, cap;
  if (r < NU) {
    row = r; cnt = cntU; cp = cpU; S = SU; rdw = rdU; cap = CAP_U;
    D = dU; Sum = sumU; base = baseU; S8 = s8U;
  } else {
    row = r - NU; cnt = cntI; cp = cpI; S = SI; rdw = rdI; cap = CAP_I;
    D = dI; Sum = sumI; base = baseI; S8 = s8I;
  }
  int p0 = row * cap, p1 = p0 + cnt[row];
  f32x4 acc = {0.f, 0.f, 0.f, 0.f};
  int p = p0;
  for (; p + 4 <= p1; p += 4) {            // 4 gathers in flight per group
    int c0 = cp[p], c1 = cp[p + 1], c2 = cp[p + 2], c3 = cp[p + 3];
    float v0 = cp_weight(c0, rdw, p, shift);
    float v1 = cp_weight(c1, rdw, p + 1, shift);
    float v2 = cp_weight(c2, rdw, p + 2, shift);
    float v3 = cp_weight(c3, rdw, p + 3, shift);
    uint32_t a0 = (v0 != 0.f) ? (uint32_t)(c0 & 0x1FFFF) : 0u;  // dummy-row
    uint32_t a1 = (v1 != 0.f) ? (uint32_t)(c1 & 0x1FFFF) : 0u;  // redirect
    uint32_t a2 = (v2 != 0.f) ? (uint32_t)(c2 & 0x1FFFF) : 0u;
    uint32_t a3 = (v3 != 0.f) ? (uint32_t)(c3 & 0x1FFFF) : 0u;
    uint32_t w0 = *(const uint32_t*)(S + ((size_t)a0 << 6) + l15 * 4);
    uint32_t w1 = *(const uint32_t*)(S + ((size_t)a1 << 6) + l15 * 4);
    uint32_t w2 = *(const uint32_t*)(S + ((size_t)a2 << 6) + l15 * 4);
    uint32_t w3 = *(const uint32_t*)(S + ((size_t)a3 << 6) + l15 * 4);
    f32x4 f0 = fp8_to4(w0), f1 = fp8_to4(w1), f2 = fp8_to4(w2), f3 = fp8_to4(w3);
#pragma unroll
    for (int k = 0; k < 4; ++k)
      acc[k] += (v0 * f0[k] + v1 * f1[k]) + (v2 * f2[k] + v3 * f3[k]);
  }
  for (; p < p1; ++p) {
    int c0 = cp[p];
    float v0 = cp_weight(c0, rdw, p, shift);
    if (v0 != 0.f) {
      uint32_t w0 = *(const uint32_t*)(S + ((size_t)(uint32_t)(c0 & 0x1FFFF) << 6) + l15 * 4);
      f32x4 f0 = fp8_to4(w0);
#pragma unroll
      for (int k = 0; k < 4; ++k) acc[k] += v0 * f0[k];
    }
  }
  size_t idx = (size_t)row * DD + l15 * 4;
  if (D) {
    *(uint32_t*)(D + idx) = pack4_fp8(acc[0] * (4.0f / 3.0f), acc[1] * (4.0f / 3.0f),
                                      acc[2] * (4.0f / 3.0f), acc[3] * (4.0f / 3.0f));
    float4 b4 = *(const float4*)(base + idx);
    ushort4 s;
    s.x = f2bf(b4.x + acc[0] * SPMM_DESCALE);
    s.y = f2bf(b4.y + acc[1] * SPMM_DESCALE);
    s.z = f2bf(b4.z + acc[2] * SPMM_DESCALE);
    s.w = f2bf(b4.w + acc[3] * SPMM_DESCALE);
    *(ushort4*)(Sum + idx) = s;
  } else {
    ushort4 s = *(const ushort4*)(Sum + idx);
    float s0 = bf2f(s.x) + acc[0] * SPMM_DESCALE;
    float s1 = bf2f(s.y) + acc[1] * SPMM_DESCALE;
    float s2 = bf2f(s.z) + acc[2] * SPMM_DESCALE;
    float s3 = bf2f(s.w) + acc[3] * SPMM_DESCALE;
    s.x = f2bf(s0); s.y = f2bf(s1); s.z = f2bf(s2); s.w = f2bf(s3);
    *(ushort4*)(Sum + idx) = s;
    if (S8)   // sums -> dword1 slot of the interleaved table (128B rows)
      *(uint32_t*)(S8 + ((size_t)row << 7) + l15 * 8 + 4) =
          pack4_fp8(s0 * FP8_SCALE, s1 * FP8_SCALE, s2 * FP8_SCALE, s3 * FP8_SCALE);
  }
}

// prop1-L0 with FUSED edge-logit on interleaved tables: ONE dwordx2 gather
// per entry brings {base dword (spmm operand), sum dword (logit operand)}.
// 4 entries in flight. aug written SEQUENTIALLY (u16) at wr[p] for prop1-L1.
__global__ __launch_bounds__(256)
void spmm_aug_kernel(const int* __restrict__ cntU, const int* __restrict__ cpU,
                     const int* __restrict__ cntI, const int* __restrict__ cpI,
                     const uint8_t* __restrict__ TU, const uint8_t* __restrict__ TI,
                     uint8_t* __restrict__ dU, uint8_t* __restrict__ dI,
                     uint16_t* __restrict__ sumU, uint16_t* __restrict__ sumI,
                     const float* __restrict__ baseU, const float* __restrict__ baseI,
                     uint16_t* __restrict__ wrU, uint16_t* __restrict__ wrI) {
  int lane = threadIdx.x & 63;
  int g = lane >> 4, l15 = lane & 15;
  int w = (blockIdx.x * blockDim.x + threadIdx.x) >> 6;
  int r = w * 4 + g;
  const int* cnt; const int* cp; const uint8_t *T, *Rt;
  uint8_t* D; uint16_t* Sum; const float* base; uint16_t* wr; int row, cap;
  if (r < NU) {
    row = r; cnt = cntU; cp = cpU; T = TI; Rt = TU; cap = CAP_U;
    D = dU; Sum = sumU; base = baseU; wr = wrU;
  } else {
    row = r - NU; cnt = cntI; cp = cpI; T = TU; Rt = TI; cap = CAP_I;
    D = dI; Sum = sumI; base = baseI; wr = wrI;
  }
  // row-side logit vector (128x-scaled fp8 sums -> float), dword1 of own row
  uint32_t rv = *(const uint32_t*)(Rt + ((size_t)row << 7) + l15 * 8 + 4);
  f32x4 rr = fp8_to4(rv);
  int p0 = row * cap, p1 = p0 + cnt[row];
  f32x4 acc = {0.f, 0.f, 0.f, 0.f};
  int p = p0;
  for (; p + 4 <= p1; p += 4) {
    int c0 = cp[p], c1 = cp[p + 1], c2 = cp[p + 2], c3 = cp[p + 3];
    uint2 sg0 = *(const uint2*)(T + ((size_t)(uint32_t)(c0 & 0x1FFFF) << 7) + l15 * 8);
    uint2 sg1 = *(const uint2*)(T + ((size_t)(uint32_t)(c1 & 0x1FFFF) << 7) + l15 * 8);
    uint2 sg2 = *(const uint2*)(T + ((size_t)(uint32_t)(c2 & 0x1FFFF) << 7) + l15 * 8);
    uint2 sg3 = *(const uint2*)(T + ((size_t)(uint32_t)(c3 & 0x1FFFF) << 7) + l15 * 8);
    f32x4 g0 = fp8_to4(sg0.y), g1 = fp8_to4(sg1.y);
    f32x4 g2 = fp8_to4(sg2.y), g3 = fp8_to4(sg3.y);
    float d0 = rr[0] * g0[0] + rr[1] * g0[1] + rr[2] * g0[2] + rr[3] * g0[3];
    float d1 = rr[0] * g1[0] + rr[1] * g1[1] + rr[2] * g1[2] + rr[3] * g1[3];
    float d2 = rr[0] * g2[0] + rr[1] * g2[1] + rr[2] * g2[2] + rr[3] * g2[3];
    float d3 = rr[0] * g3[0] + rr[1] * g3[1] + rr[2] * g3[2] + rr[3] * g3[3];
#pragma unroll
    for (int o = 1; o < 16; o <<= 1) {
      d0 += __shfl_xor(d0, o, 16);
      d1 += __shfl_xor(d1, o, 16);
      d2 += __shfl_xor(d2, o, 16);
      d3 += __shfl_xor(d3, o, 16);
    }
    float a0 = (float)(((uint32_t)c0) >> 21) * AV_DEC / (1.0f + __expf(-d0 * EL_DESCALE));
    float a1 = (float)(((uint32_t)c1) >> 21) * AV_DEC / (1.0f + __expf(-d1 * EL_DESCALE));
    float a2 = (float)(((uint32_t)c2) >> 21) * AV_DEC / (1.0f + __expf(-d2 * EL_DESCALE));
    float a3 = (float)(((uint32_t)c3) >> 21) * AV_DEC / (1.0f + __expf(-d3 * EL_DESCALE));
    if (l15 == 0) {
      wr[p] = (uint16_t)(a0 * AUG_ENC + 0.5f);
      wr[p + 1] = (uint16_t)(a1 * AUG_ENC + 0.5f);
      wr[p + 2] = (uint16_t)(a2 * AUG_ENC + 0.5f);
      wr[p + 3] = (uint16_t)(a3 * AUG_ENC + 0.5f);
    }
    float v0 = a0 * (float)((c0 >> 19) & 1);
    float v1 = a1 * (float)((c1 >> 19) & 1);
    float v2 = a2 * (float)((c2 >> 19) & 1);
    float v3 = a3 * (float)((c3 >> 19) & 1);
    f32x4 f0 = fp8_to4(sg0.x), f1 = fp8_to4(sg1.x);
    f32x4 f2 = fp8_to4(sg2.x), f3 = fp8_to4(sg3.x);
#pragma unroll
    for (int k = 0; k < 4; ++k)
      acc[k] += (v0 * f0[k] + v1 * f1[k]) + (v2 * f2[k] + v3 * f3[k]);
  }
  for (; p < p1; ++p) {
    int c0 = cp[p];
    uint2 sg0 = *(const uint2*)(T + ((size_t)(uint32_t)(c0 & 0x1FFFF) << 7) + l15 * 8);
    f32x4 g0 = fp8_to4(sg0.y);
    float d0 = rr[0] * g0[0] + rr[1] * g0[1] + rr[2] * g0[2] + rr[3] * g0[3];
#pragma unroll
    for (int o = 1; o < 16; o <<= 1) d0 += __shfl_xor(d0, o, 16);
    float a0 = (float)(((uint32_t)c0) >> 21) * AV_DEC / (1.0f + __expf(-d0 * EL_DESCALE));
    if (l15 == 0) wr[p] = (uint16_t)(a0 * AUG_ENC + 0.5f);
    float v0 = a0 * (float)((c0 >> 19) & 1);
    f32x4 f0 = fp8_to4(sg0.x);
#pragma unroll
    for (int k = 0; k < 4; ++k) acc[k] += v0 * f0[k];
  }
  size_t idx = (size_t)row * DD + l15 * 4;
  *(uint32_t*)(D + idx) = pack4_fp8(acc[0] * (4.0f / 3.0f), acc[1] * (4.0f / 3.0f),
                                    acc[2] * (4.0f / 3.0f), acc[3] * (4.0f / 3.0f));
  float4 b4 = *(const float4*)(base + idx);
  ushort4 s;
  s.x = f2bf(b4.x + acc[0] * SPMM_DESCALE);
  s.y = f2bf(b4.y + acc[1] * SPMM_DESCALE);
  s.z = f2bf(b4.z + acc[2] * SPMM_DESCALE);
  s.w = f2bf(b4.w + acc[3] * SPMM_DESCALE);
  *(ushort4*)(Sum + idx) = s;
}

// base tables fp32 -> fp8(x128): COMPACT 64B-row copies (prop0-L0 gathers)
// AND the interleaved tables' dword0 slots (spmm_aug gathers), plus fused
// L2-reg sum-of-squares (Eu0,Ev0,Eb).
__global__ void cvt2_fp8_kernel(const float4* __restrict__ a, int na4,
                                uint32_t* __restrict__ oca, uint32_t* __restrict__ oia,
                                const float4* __restrict__ b, int nb4,
                                uint32_t* __restrict__ ocb, uint32_t* __restrict__ oib,
                                const float4* __restrict__ c, int nc4,
                                float* __restrict__ acc) {
  __shared__ float red[256];
  int total = na4 + nb4 + nc4;
  float s = 0.f;
  for (int i = blockIdx.x * blockDim.x + threadIdx.x; i < total; i += gridDim.x * blockDim.x) {
    float4 v = (i < na4) ? a[i] : (i < na4 + nb4) ? b[i - na4] : c[i - na4 - nb4];
    s += v.x * v.x + v.y * v.y + v.z * v.z + v.w * v.w;
    if (i < na4 + nb4) {
      uint32_t w = pack4_fp8(v.x * FP8_SCALE, v.y * FP8_SCALE, v.z * FP8_SCALE, v.w * FP8_SCALE);
      if (i < na4) {
        oca[i] = w;
        oia[((i >> 4) << 5) + ((i & 15) << 1)] = w;
      } else {
        int j = i - na4;
        ocb[j] = w;
        oib[((j >> 4) << 5) + ((j & 15) << 1)] = w;
      }
    }
  }
  red[threadIdx.x] = s;
  __syncthreads();
  for (int st = 128; st > 0; st >>= 1) {
    if (threadIdx.x < st) red[threadIdx.x] += red[threadIdx.x + st];
    __syncthreads();
  }
  if (threadIdx.x == 0) atomicAdd(&acc[7], red[0]);
}

// gather both Z row sets; PRE-SCALE by LOG2E5 so PCL's MFMA emits
// already-log2-scaled logits
__global__ void gather2_rows_kernel(const uint16_t* __restrict__ Z16u, const int* __restrict__ uids,
                                    uint16_t* __restrict__ ou,
                                    const uint16_t* __restrict__ Z16i, const int* __restrict__ iids,
                                    uint16_t* __restrict__ oi) {
  int b = blockIdx.x, lane = threadIdx.x;
  if (b < BATCH)
    ou[(size_t)b * 64 + lane] = f2bf(bf2f(Z16u[(size_t)uids[b] * 64 + lane]) * LOG2E5);
  else {
    int bb = b - BATCH;
    oi[(size_t)bb * 64 + lane] = f2bf(bf2f(Z16i[(size_t)iids[bb] * 64 + lane]) * LOG2E5);
  }
}

// PCL denominator: S[m] += sum_n exp2(dot(Zg_scaled[m],E[n])), bf16 MFMA.
// v11: occupancy scales with DISPATCHED block count (r9: 2048 blk -> 43%,
// r10: 1536 blk -> 30%, pcl slower) -> go finer: 3072 UNIFORM ~24-iter
// blocks (U: x in [0,256) SPL=256; I: x in [0,128) SPL=128), 1-deep
// prefetch (48 VGPR; r10's 2-deep cost regs for nothing).
__global__ __launch_bounds__(256)
void pcl_mfma8_kernel(const uint16_t* __restrict__ Zgu, const uint16_t* __restrict__ E16u,
                      int NTu, float* __restrict__ Su,
                      const uint16_t* __restrict__ Zgi, const uint16_t* __restrict__ E16i,
                      int NTi, float* __restrict__ Si) {
  int lane = threadIdx.x & 63;
  int wave = threadIdx.x >> 6;
  int quad = lane >> 4, l15 = lane & 15;
  int bid = blockIdx.x;
  const uint16_t *Zg, *E16; int NT, x, y, SPL; float* S;
  if (bid < 2048) {
    Zg = Zgu; E16 = E16u; NT = NTu; S = Su;
    x = bid & 255; y = bid >> 8; SPL = 256;
  } else {
    int b2 = bid - 2048;
    Zg = Zgi; E16 = E16i; NT = NTi; S = Si;
    x = b2 & 127; y = b2 >> 7; SPL = 128;
  }
  int mt0 = (y * 4 + wave) * 4;            // 4 consecutive m-tiles per wave
  bf16x8 a0[4], a1[4];
#pragma unroll
  for (int i = 0; i < 4; ++i) {
    const uint16_t* ar = Zg + (size_t)((mt0 + i) * 16 + l15) * 64 + quad * 8;
    a0[i] = *(const bf16x8*)ar;
    a1[i] = *(const bf16x8*)(ar + 32);
  }
  f32x4 rs[4] = {};
  int nt = x;
  bf16x8 b0 = {}, b1 = {};
  if (nt < NT) {
    const uint16_t* br = E16 + (size_t)(nt * 16 + l15) * 64 + quad * 8;
    b0 = *(const bf16x8*)br;
    b1 = *(const bf16x8*)(br + 32);
  }
  while (nt < NT) {
    int nn = nt + SPL;
    bf16x8 p0 = {}, p1 = {};
    if (nn < NT) {
      const uint16_t* pr = E16 + (size_t)(nn * 16 + l15) * 64 + quad * 8;
      p0 = *(const bf16x8*)pr;
      p1 = *(const bf16x8*)(pr + 32);
    }
#pragma unroll
    for (int i = 0; i < 4; ++i) {
      f32x4 c = {0.f, 0.f, 0.f, 0.f};
      c = __builtin_amdgcn_mfma_f32_16x16x32_bf16(a0[i], b0, c, 0, 0, 0);
      c = __builtin_amdgcn_mfma_f32_16x16x32_bf16(a1[i], b1, c, 0, 0, 0);
#pragma unroll
      for (int r = 0; r < 4; ++r) rs[i][r] += __builtin_amdgcn_exp2f(c[r]);
    }
    b0 = p0; b1 = p1; nt = nn;
  }
#pragma unroll
  for (int off = 8; off > 0; off >>= 1) {
#pragma unroll
    for (int i = 0; i < 4; ++i)
#pragma unroll
      for (int r = 0; r < 4; ++r) rs[i][r] += __shfl_down(rs[i][r], off, 16);
  }
  if (l15 == 0) {
#pragma unroll
    for (int i = 0; i < 4; ++i)
#pragma unroll
      for (int r = 0; r < 4; ++r)
        atomicAdd(&S[(mt0 + i) * 16 + quad * 4 + r], rs[i][r]);
  }
}

__global__ void bpr_kernel(const uint16_t* __restrict__ E16u, const uint16_t* __restrict__ E16i,
                           const int* __restrict__ uids, const int* __restrict__ pos,
                           const int* __restrict__ neg, float* __restrict__ ps,
                           float* __restrict__ acc) {
  int lane = threadIdx.x & 63;
  int b = (blockIdx.x * blockDim.x + threadIdx.x) >> 6;
  if (b >= BATCH) return;
  float u = bf2f(E16u[(size_t)uids[b] * DD + lane]);
  float p = u * bf2f(E16i[(size_t)pos[b] * DD + lane]);
  float n = u * bf2f(E16i[(size_t)neg[b] * DD + lane]);
#pragma unroll
  for (int off = 32; off > 0; off >>= 1) { p += __shfl_down(p, off); n += __shfl_down(n, off); }
  if (lane == 0) {
    ps[b] = p;
    float x = p - n;
    atomicAdd(&acc[0], logf(1.0f / (1.0f + __expf(-x))));
  }
}

__global__ void minmax_kernel(const float* __restrict__ ps, float* __restrict__ mm) {
  __shared__ float smn[256], smx[256];
  int tid = threadIdx.x;
  float mn = 3.0e38f, mx = -3.0e38f;
  for (int i = tid; i < BATCH; i += 256) { float v = ps[i]; mn = fminf(mn, v); mx = fmaxf(mx, v); }
  smn[tid] = mn; smx[tid] = mx;
  __syncthreads();
  for (int s = 128; s > 0; s >>= 1) {
    if (tid < s) { smn[tid] = fminf(smn[tid], smn[tid + s]); smx[tid] = fmaxf(smx[tid], smx[tid + s]); }
    __syncthreads();
  }
  if (tid == 0) { mm[0] = smn[0]; mm[1] = smx[0]; }
}

__global__ void bcl_kernel(const uint16_t* __restrict__ E16u, const uint16_t* __restrict__ E16i,
                           const float* __restrict__ Eb, const int* __restrict__ uids,
                           const int* __restrict__ pos, const float* __restrict__ ps,
                           const float* __restrict__ mm, float* __restrict__ acc) {
  int lane = threadIdx.x & 63;
  int b = (blockIdx.x * blockDim.x + threadIdx.x) >> 6;
  if (b >= BATCH) return;
  float wgt = (ps[b] - mm[0]) / (mm[1] - mm[0] + 1e-9f);
  int rel = (int)(wgt * 10.0f);
  rel = rel < 0 ? 0 : (rel > 9 ? 9 : rel);
  float x = bf2f(E16u[(size_t)uids[b] * DD + lane]) * bf2f(E16i[(size_t)pos[b] * DD + lane]);
  float el = 1.0f / (1.0f + __expf(-x));
  float sneg = 0.f, spos = 0.f;
  for (int k = 0; k < NBK; ++k) {
    float d = el * Eb[k * DD + lane];
#pragma unroll
    for (int off = 32; off > 0; off >>= 1) d += __shfl_down(d, off);
    if (lane == 0) { if (k == rel) spos = d; else sneg += d; }
  }
  if (lane == 0) {
    atomicAdd(&acc[5], sneg * 0.1f);
    atomicAdd(&acc[6], spos);
  }
}

__global__ void pclpos2_kernel(const uint16_t* __restrict__ Z16u, const uint16_t* __restrict__ E16u,
                               const int* __restrict__ uids,
                               const uint16_t* __restrict__ Z16i, const uint16_t* __restrict__ E16i,
                               const int* __restrict__ iids, float* __restrict__ acc) {
  int lane = threadIdx.x & 63;
  int b = (blockIdx.x * blockDim.x + threadIdx.x) >> 6;
  if (b >= 2 * BATCH) return;
  const uint16_t *Z, *E; const int* ids; int idx, bb;
  if (b < BATCH) { Z = Z16u; E = E16u; ids = uids; idx = 3; bb = b; }
  else { Z = Z16i; E = E16i; ids = iids; idx = 4; bb = b - BATCH; }
  size_t r = (size_t)ids[bb] * DD + lane;
  float p = bf2f(Z[r]) * bf2f(E[r]);
#pragma unroll
  for (int off = 32; off > 0; off >>= 1) p += __shfl_down(p, off);
  if (lane == 0) {
    float x = p * 5.0f;
    x = fminf(5.0f, fmaxf(-5.0f, x));
    atomicAdd(&acc[idx], x);
  }
}

__global__ void finalize_kernel(const float* __restrict__ Su, const float* __restrict__ Si,
                                const float* __restrict__ acc, float* __restrict__ out) {
  __shared__ float r1[256], r2[256];
  int tid = threadIdx.x;
  float su = 0.f, si = 0.f;
  for (int b = tid; b < BATCH; b += 256) {
    su += logf(Su[b] + 1e-8f);
    si += logf(Si[b] + 1e-8f);
  }
  r1[tid] = su; r2[tid] = si;
  __syncthreads();
  for (int s = 128; s > 0; s >>= 1) {
    if (tid < s) { r1[tid] += r1[tid + s]; r2[tid] += r2[tid + s]; }
    __syncthreads();
  }
  if (tid == 0) {
    const float inv = 1.0f / (float)BATCH;
    float neg_s = (r1[0] + r2[0]) * inv;
    float pos_s = (acc[3] + acc[4]) * inv;
    float pcl = neg_s - pos_s;
    float bpr = -acc[0] * inv;
    float bcl = (acc[5] - acc[6]) * inv;
    float reg = 1e-7f * acc[7];
    float loss = bpr + 0.2f * pcl + 0.2f * bcl + reg;
    out[0] = loss; out[1] = bpr; out[2] = 0.2f * pcl; out[3] = 0.2f * bcl;
  }
}

extern "C" void kernel_launch(void* const* d_in, const int* in_sizes, int n_in,
                              void* d_out, int out_size, void* d_ws, size_t ws_size,
                              hipStream_t stream) {
  (void)in_sizes; (void)n_in; (void)out_size; (void)ws_size;
  const float* Eu0 = (const float*)d_in[0];
  const float* Ev0 = (const float*)d_in[1];
  const float* Eb  = (const float*)d_in[2];
  const float* av  = (const float*)d_in[3];
  const int* rows  = (const int*)d_in[4];
  const int* cols  = (const int*)d_in[5];
  const int* uids  = (const int*)d_in[6];
  const int* iids  = (const int*)d_in[7];
  const int* pos   = (const int*)d_in[8];
  const int* neg   = (const int*)d_in[9];
  float* out = (float*)d_out;

  float* w = (float*)d_ws;
  size_t o = 0;
  float* ps  = w + o; o += BATCH;
  float* Su  = w + o; o += BATCH;
  float* Si  = w + o; o += BATCH;
  float* acc = w + o; o += 16;
  float* mm  = w + o; o += 2;
  // bf16 running-sum tables + gathered Z rows + u16 aug streams
  uint16_t* hp = (uint16_t*)(w + o);
  uint16_t* E16u = hp; hp += (size_t)NU * DD;
  uint16_t* E16i = hp; hp += (size_t)NI * DD;
  uint16_t* Z16u = hp; hp += (size_t)NU * DD;
  uint16_t* Z16i = hp; hp += (size_t)NI * DD;
  uint16_t* Zgu  = hp; hp += (size_t)BATCH * DD;
  uint16_t* Zgi  = hp; hp += (size_t)BATCH * DD;
  uint16_t* augU = hp; hp += (size_t)NU * CAP_U + 64;  // aug weights (u16, bucket order)
  uint16_t* augI = hp; hp += (size_t)NI * CAP_I + 64;
  // fp8 tables
  uint8_t* bp = (uint8_t*)hp;
  uint8_t* TU  = bp; bp += (size_t)NU * 128;    // interleaved {base, sum} 128B rows
  uint8_t* TI  = bp; bp += (size_t)NI * 128;
  uint8_t* E0u8 = bp; bp += (size_t)NU * DD;    // compact base (prop0-L0 gathers)
  uint8_t* E0v8 = bp; bp += (size_t)NI * DD;
  uint8_t* d8U = bp; bp += (size_t)NU * DD;     // layer0 outs (fp8, 128x, plain 64B)
  uint8_t* d8I = bp; bp += (size_t)NI * DD;
  uint8_t* mask8 = bp; bp += NE;
  // int region (8B aligned): fill counters + bucket cp arrays
  int* ip = (int*)(((uintptr_t)bp + 7) & ~(uintptr_t)7);
  int* cntU = ip; ip += NU;
  int* cntI = ip; ip += NI;
  int* cpU = ip; ip += (size_t)NU * CAP_U + 64;
  int* cpI = ip; ip += (size_t)NI * CAP_I + 64;

  // key chain: key(42) = (0,42); fold_in(k,d) = threefry2x32(k, [0,d])
  uint32_t bk[2][2];
  tf2x32(0u, 42u, 0u, 0u, bk[0][0], bk[0][1]);
  tf2x32(0u, 42u, 0u, 1u, bk[1][0], bk[1][1]);
  Keys8 K;
  for (int p = 0; p < 2; ++p)
    for (int l = 0; l < 2; ++l) {
      tf2x32(bk[p][0], bk[p][1], 0u, (uint32_t)(2 * l),     K.k[p * 2 + l][0], K.k[p * 2 + l][1]);
      tf2x32(bk[p][0], bk[p][1], 0u, (uint32_t)(2 * l + 1), K.k[4 + p * 2 + l][0], K.k[4 + p * 2 + l][1]);
    }

  // acc must be zero before cvt2 (fused sumsq accumulates acc[7])
  (void)hipMemsetAsync(ps, 0, (3 * BATCH + 18) * sizeof(float), stream);
  cvt2_fp8_kernel<<<2048, 256, 0, stream>>>(
      (const float4*)Eu0, NU * DD / 4, (uint32_t*)E0u8, (uint32_t*)TU,
      (const float4*)Ev0, NI * DD / 4, (uint32_t*)E0v8, (uint32_t*)TI,
      (const float4*)Eb, NBK * DD / 4, acc);
  mask_kernel<<<(NE / 2 + 255) / 256, 256, 0, stream>>>(mask8, K);
  (void)hipMemsetAsync(cntU, 0, (size_t)(NU + NI) * sizeof(int), stream);
  // bucket scatter (hist + scan deleted in v8)
  scatter_kernel<<<NCHUNK * NSLICE, 256, 0, stream>>>(rows, cols, mask8, av,
                                                      cntU, cntI, cpU, cpI);

  const int SPB = (NU + NI) / 16;   // 4 rows/wave, 4 waves/block -> 9375 blocks

  // ---- propagation 0 (mask bits 17/18, packed av weights; compact tables) ----
  spmm_layer_kernel<<<SPB, 256, 0, stream>>>(cntU, cpU, cntI, cpI, nullptr, nullptr, 17,
                                             E0v8, E0u8, d8U, d8I,
                                             E16u, E16i, Eu0, Ev0, nullptr, nullptr);
  spmm_layer_kernel<<<SPB, 256, 0, stream>>>(cntU, cpU, cntI, cpI, nullptr, nullptr, 18,
                                             d8I, d8U, nullptr, nullptr,
                                             E16u, E16i, nullptr, nullptr, TU, TI);

  // ---- propagation 1 layer 0 + fused edge-logit (bit 19; writes augU/augI) ----
  spmm_aug_kernel<<<SPB, 256, 0, stream>>>(cntU, cpU, cntI, cpI, TU, TI,
                                           d8U, d8I, Z16u, Z16i, Eu0, Ev0,
                                           augU, augI);
  // ---- propagation 1 layer 1 (bit 20, sequential u16 aug weights) ----
  spmm_layer_kernel<<<SPB, 256, 0, stream>>>(cntU, cpU, cntI, cpI, augU, augI, 20,
                                             d8I, d8U, nullptr, nullptr,
                                             Z16u, Z16i, nullptr, nullptr, nullptr, nullptr);

  gather2_rows_kernel<<<2 * BATCH, 64, 0, stream>>>(Z16u, uids, Zgu, Z16i, iids, Zgi);

  bpr_kernel<<<BATCH / 4, 256, 0, stream>>>(E16u, E16i, uids, pos, neg, ps, acc);
  minmax_kernel<<<1, 256, 0, stream>>>(ps, mm);
  bcl_kernel<<<BATCH / 4, 256, 0, stream>>>(E16u, E16i, Eb, uids, pos, ps, mm, acc);

  // PCL denominators: 3072 uniform ~24-iter blocks (2048 U SPL=256 +
  // 1024 I SPL=128) -- occupancy scales with dispatched block count
  pcl_mfma8_kernel<<<3072, 256, 0, stream>>>(Zgu, E16u, NU / 16, Su,
                                             Zgi, E16i, NI / 16, Si);

  pclpos2_kernel<<<2 * BATCH / 4, 256, 0, stream>>>(Z16u, E16u, uids, Z16i, E16i, iids, acc);

  finalize_kernel<<<1, 256, 0, stream>>>(Su, Si, acc, out);
}

// Round 12
// 694.596 us; speedup vs baseline: 1.0721x; 1.0721x over previous
//
#include <hip/hip_runtime.h>
#include <stdint.h>

#define NU 100000
#define NI 50000
#define NBK 10
#define DD 64
#define NE 1000000
#define BATCH 2048
#define NSLICE 8
#define USLICE ((NU + NSLICE - 1) / NSLICE)   // 12500
#define ISLICE ((NI + NSLICE - 1) / NSLICE)   // 6250
#define NCHUNK 512
#define EPC ((NE + NCHUNK - 1) / NCHUNK)      // 1954
// row bucket capacities: degrees are Poisson(10) U / Poisson(20) I;
// P(any row exceeds) < 1e-5 overall, +64-entry allocation slack.
#define CAP_U 36
#define CAP_I 56
// fp8 storage scale: embeddings ~0.01 are subnormal in e4m3; x128 -> normal.
// Combined descale: (4/3 dropout) / 128 = 1/96.
#define FP8_SCALE 128.0f
#define SPMM_DESCALE (1.0f / 96.0f)
#define EL_DESCALE (1.0f / 16384.0f)   // edge-logit dot of two 128x fp8 tables
#define LOG2E5 7.2134752f              // 5*log2(e): exp(5x) = 2^(x*LOG2E5)
// av in [0, 0.05): 11-bit fixed point in cp bits 21..31 (cp entry = ONE int:
// col 17b | mask 4b @17 | av 11b @21).
#define AV_ENC 40960.0f                // 2^11 / 0.05
#define AV_DEC (0.05f / 2048.0f)
// aug weights stored u16 fixed-point (rel err ~2e-5, << fp8 table error)
#define AUG_ENC (65535.0f / 0.05f)
#define AUG_DEC (0.05f / 65535.0f)

typedef __bf16 bf16x8 __attribute__((ext_vector_type(8)));
typedef float f32x4 __attribute__((ext_vector_type(4)));
typedef float f32x2 __attribute__((ext_vector_type(2)));

struct Keys8 { uint32_t k[8][2]; };

// ---------------- threefry2x32 (JAX-compatible, 20 rounds) ----------------
__host__ __device__ inline void tf2x32(uint32_t k0, uint32_t k1, uint32_t x0, uint32_t x1,
                                       uint32_t& o0, uint32_t& o1) {
  uint32_t ks0 = k0, ks1 = k1, ks2 = k0 ^ k1 ^ 0x1BD11BDAu;
  x0 += ks0; x1 += ks1;
#define TFR(r) { x0 += x1; x1 = (x1 << (r)) | (x1 >> (32 - (r))); x1 ^= x0; }
  TFR(13) TFR(15) TFR(26) TFR(6)   x0 += ks1; x1 += ks2 + 1u;
  TFR(17) TFR(29) TFR(16) TFR(24)  x0 += ks2; x1 += ks0 + 2u;
  TFR(13) TFR(15) TFR(26) TFR(6)   x0 += ks0; x1 += ks1 + 3u;
  TFR(17) TFR(29) TFR(16) TFR(24)  x0 += ks1; x1 += ks2 + 4u;
  TFR(13) TFR(15) TFR(26) TFR(6)   x0 += ks2; x1 += ks0 + 5u;
#undef TFR
  o0 = x0; o1 = x1;
}

__device__ inline uint16_t f2bf(float f) {
  uint32_t u = __float_as_uint(f);
  return (uint16_t)((u + 0x7fffu + ((u >> 16) & 1u)) >> 16);   // RNE
}
__device__ inline float bf2f(uint16_t u) {
  return __uint_as_float(((uint32_t)u) << 16);
}

// ---- fp8 e4m3 (OCP) helpers ----
template <int SEL>
__device__ inline float fp8_sel(uint32_t w) {
#if __has_builtin(__builtin_amdgcn_cvt_f32_fp8)
  return __builtin_amdgcn_cvt_f32_fp8((int)w, SEL);
#else
  uint32_t b = (w >> (8 * SEL)) & 0xFFu;
  uint32_t s = b >> 7, e = (b >> 3) & 0xF, m = b & 7;
  float v = (e == 0) ? (float)m * (1.0f / 512.0f)
                     : __uint_as_float(((e + 120) << 23) | (m << 20));
  return s ? -v : v;
#endif
}
// packed decode: one dword of 4 fp8 -> f32x4 via 2x v_cvt_pk_f32_fp8
__device__ inline f32x4 fp8_to4(uint32_t w) {
#if __has_builtin(__builtin_amdgcn_cvt_pk_f32_fp8)
  f32x2 lo = __builtin_amdgcn_cvt_pk_f32_fp8((int)w, false);
  f32x2 hi = __builtin_amdgcn_cvt_pk_f32_fp8((int)w, true);
  f32x4 r; r[0] = lo[0]; r[1] = lo[1]; r[2] = hi[0]; r[3] = hi[1];
  return r;
#else
  f32x4 r; r[0] = fp8_sel<0>(w); r[1] = fp8_sel<1>(w);
  r[2] = fp8_sel<2>(w); r[3] = fp8_sel<3>(w);
  return r;
#endif
}
__device__ inline uint32_t f32_to_fp8(float f) {
#if __has_builtin(__builtin_amdgcn_cvt_pk_fp8_f32)
  return (uint32_t)__builtin_amdgcn_cvt_pk_fp8_f32(f, f, 0, false) & 0xFFu;
#else
  uint32_t s = (__float_as_uint(f) >> 31) << 7;
  float a = fabsf(f);
  a = fminf(a, 448.0f);
  if (a < 0.015625f) {
    uint32_t m = (uint32_t)(a * 512.0f + 0.5f);
    return s | m;
  }
  int ex; float fr = frexpf(a, &ex);
  uint32_t q = (uint32_t)(fr * 16.0f + 0.5f);
  int E = ex + 6;
  if (q == 16) { q = 8; E += 1; }
  if (E > 15) { E = 15; q = 14; }
  if (E == 15 && q == 15) q = 14;
  return s | ((uint32_t)E << 3) | (q - 8);
#endif
}
__device__ inline uint32_t pack4_fp8(float a, float b, float c, float d) {
  return f32_to_fp8(a) | (f32_to_fp8(b) << 8) | (f32_to_fp8(c) << 16) | (f32_to_fp8(d) << 24);
}

// dropout masks for edge pair (e, e+half) from ONE threefry eval per key:
// o0 -> element e, o1 -> element e+half (JAX split-iota semantics).
__global__ void mask_kernel(uint8_t* __restrict__ mask, Keys8 K) {
  const int half = NE / 2;
  int e = blockIdx.x * blockDim.x + threadIdx.x;
  if (e >= half) return;
  uint32_t mlo = 0, mhi = 0;
#pragma unroll
  for (int j = 0; j < 8; ++j) {
    uint32_t o0, o1;
    tf2x32(K.k[j][0], K.k[j][1], (uint32_t)e, (uint32_t)(e + half), o0, o1);
    float u0 = __uint_as_float((o0 >> 9) | 0x3f800000u) - 1.0f;
    float u1 = __uint_as_float((o1 >> 9) | 0x3f800000u) - 1.0f;
    mlo |= (u0 < 0.75f ? 1u : 0u) << j;
    mhi |= (u1 < 0.75f ? 1u : 0u) << j;
  }
  mask[e] = (uint8_t)mlo;
  mask[e + half] = (uint8_t)mhi;
}

// XCD-sliced bucket scatter (slice = blockIdx&7; L2-local atomics per round-2
// measurement). Fixed-capacity ROW BUCKETS self-allocated by atomicAdd.
// ~90-104us across 6 structural variants -> atomic/latency floor; left as-is.
__global__ __launch_bounds__(256)
void scatter_kernel(const int* __restrict__ rows, const int* __restrict__ cols,
                    const uint8_t* __restrict__ mask, const float* __restrict__ av,
                    int* __restrict__ cntU, int* __restrict__ cntI,
                    int* __restrict__ cpU, int* __restrict__ cpI) {
  int slice = blockIdx.x & 7;
  int chunk = blockIdx.x >> 3;
  int base = chunk * EPC;
  int end = base + EPC; if (end > NE) end = NE;
  for (int e = base + threadIdx.x; e < end; e += 256) {
    int r = __builtin_nontemporal_load(rows + e);
    int c = __builtin_nontemporal_load(cols + e);
    uint32_t m = __builtin_nontemporal_load(mask + e);
    float a = __builtin_nontemporal_load(av + e);
    uint32_t q = (uint32_t)(a * AV_ENC + 0.5f);
    if (q > 2047u) q = 2047u;
    uint32_t qb = q << 21;
    if (r / USLICE == slice) {
      int old = atomicAdd(&cntU[r], 1);
      cpU[r * CAP_U + old] = (int)((uint32_t)c | ((m & 0xFu) << 17) | qb);
    }
    if (c / ISLICE == slice) {
      int old = atomicAdd(&cntI[c], 1);
      cpI[c * CAP_I + old] = (int)((uint32_t)r | (((m >> 4) & 0xFu) << 17) | qb);
    }
  }
}

// weight: rdw!=null -> sequential u16 aug stream (prop1-L1); else decode the
// 11-bit packed av (prop0, no memory access).
__device__ inline float cp_weight(int cc, const uint16_t* __restrict__ rdw, int p, int shift) {
  float mb = (float)((cc >> shift) & 1);
  if (rdw) return (float)rdw[p] * AUG_DEC * mb;
  return (float)(((uint32_t)cc) >> 21) * AV_DEC * mb;
}

// merged U+I gather-reduce SpMM, sub-wave layout: wave = 4 rows x 16 lanes,
// lane covers 4 dims via one dword fp8 load. Zero-weight entries redirect
// their gather to row 0 (branchless; row 0 becomes L1/L2-hot).
__global__ __launch_bounds__(256)
void spmm_layer_kernel(const int* __restrict__ cntU, const int* __restrict__ cpU,
                       const int* __restrict__ cntI, const int* __restrict__ cpI,
                       const uint16_t* __restrict__ rdU, const uint16_t* __restrict__ rdI,
                       int shift,
                       const uint8_t* __restrict__ SU, const uint8_t* __restrict__ SI,
                       uint8_t* __restrict__ dU, uint8_t* __restrict__ dI,
                       uint16_t* __restrict__ sumU, uint16_t* __restrict__ sumI,
                       const float* __restrict__ baseU, const float* __restrict__ baseI,
                       uint8_t* __restrict__ s8U, uint8_t* __restrict__ s8I) {
  int lane = threadIdx.x & 63;
  int g = lane >> 4, l15 = lane & 15;
  int w = (blockIdx.x * blockDim.x + threadIdx.x) >> 6;
  int r = w * 4 + g;                       // NU%4==0 -> wave never straddles U/I
  const int* cnt; const int* cp; const uint8_t* S; const uint16_t* rdw;
  uint8_t* D; uint16_t* Sum; const float* base; uint8_t* S8; int row, cap;
  if (r < NU) {
    row = r; cnt = cntU; cp = cpU; S = SU; rdw = rdU; cap = CAP_U;
    D = dU; Sum = sumU; base = baseU; S8 = s8U;
  } else {
    row = r - NU; cnt = cntI; cp = cpI; S = SI; rdw = rdI; cap = CAP_I;
    D = dI; Sum = sumI; base = baseI; S8 = s8I;
  }
  int p0 = row * cap, p1 = p0 + cnt[row];
  f32x4 acc = {0.f, 0.f, 0.f, 0.f};
  int p = p0;
  for (; p + 4 <= p1; p += 4) {            // 4 gathers in flight per group
    int c0 = cp[p], c1 = cp[p + 1], c2 = cp[p + 2], c3 = cp[p + 3];
    float v0 = cp_weight(c0, rdw, p, shift);
    float v1 = cp_weight(c1, rdw, p + 1, shift);
    float v2 = cp_weight(c2, rdw, p + 2, shift);
    float v3 = cp_weight(c3, rdw, p + 3, shift);
    uint32_t a0 = (v0 != 0.f) ? (uint32_t)(c0 & 0x1FFFF) : 0u;  // dummy-row
    uint32_t a1 = (v1 != 0.f) ? (uint32_t)(c1 & 0x1FFFF) : 0u;  // redirect
    uint32_t a2 = (v2 != 0.f) ? (uint32_t)(c2 & 0x1FFFF) : 0u;
    uint32_t a3 = (v3 != 0.f) ? (uint32_t)(c3 & 0x1FFFF) : 0u;
    uint32_t w0 = *(const uint32_t*)(S + ((size_t)a0 << 6) + l15 * 4);
    uint32_t w1 = *(const uint32_t*)(S + ((size_t)a1 << 6) + l15 * 4);
    uint32_t w2 = *(const uint32_t*)(S + ((size_t)a2 << 6) + l15 * 4);
    uint32_t w3 = *(const uint32_t*)(S + ((size_t)a3 << 6) + l15 * 4);
    f32x4 f0 = fp8_to4(w0), f1 = fp8_to4(w1), f2 = fp8_to4(w2), f3 = fp8_to4(w3);
#pragma unroll
    for (int k = 0; k < 4; ++k)
      acc[k] += (v0 * f0[k] + v1 * f1[k]) + (v2 * f2[k] + v3 * f3[k]);
  }
  for (; p < p1; ++p) {
    int c0 = cp[p];
    float v0 = cp_weight(c0, rdw, p, shift);
    if (v0 != 0.f) {
      uint32_t w0 = *(const uint32_t*)(S + ((size_t)(uint32_t)(c0 & 0x1FFFF) << 6) + l15 * 4);
      f32x4 f0 = fp8_to4(w0);
#pragma unroll
      for (int k = 0; k < 4; ++k) acc[k] += v0 * f0[k];
    }
  }
  size_t idx = (size_t)row * DD + l15 * 4;
  if (D) {
    *(uint32_t*)(D + idx) = pack4_fp8(acc[0] * (4.0f / 3.0f), acc[1] * (4.0f / 3.0f),
                                      acc[2] * (4.0f / 3.0f), acc[3] * (4.0f / 3.0f));
    float4 b4 = *(const float4*)(base + idx);
    ushort4 s;
    s.x = f2bf(b4.x + acc[0] * SPMM_DESCALE);
    s.y = f2bf(b4.y + acc[1] * SPMM_DESCALE);
    s.z = f2bf(b4.z + acc[2] * SPMM_DESCALE);
    s.w = f2bf(b4.w + acc[3] * SPMM_DESCALE);
    *(ushort4*)(Sum + idx) = s;
  } else {
    ushort4 s = *(const ushort4*)(Sum + idx);
    float s0 = bf2f(s.x) + acc[0] * SPMM_DESCALE;
    float s1 = bf2f(s.y) + acc[1] * SPMM_DESCALE;
    float s2 = bf2f(s.z) + acc[2] * SPMM_DESCALE;
    float s3 = bf2f(s.w) + acc[3] * SPMM_DESCALE;
    s.x = f2bf(s0); s.y = f2bf(s1); s.z = f2bf(s2); s.w = f2bf(s3);
    *(ushort4*)(Sum + idx) = s;
    if (S8)   // sums -> dword1 slot of the interleaved table (128B rows)
      *(uint32_t*)(S8 + ((size_t)row << 7) + l15 * 8 + 4) =
          pack4_fp8(s0 * FP8_SCALE, s1 * FP8_SCALE, s2 * FP8_SCALE, s3 * FP8_SCALE);
  }
}

// prop1-L0 with FUSED edge-logit on interleaved tables: ONE dwordx2 gather
// per entry brings {base dword (spmm operand), sum dword (logit operand)}.
// 4 entries in flight. aug written SEQUENTIALLY (u16) at wr[p] for prop1-L1.
__global__ __launch_bounds__(256)
void spmm_aug_kernel(const int* __restrict__ cntU, const int* __restrict__ cpU,
                     const int* __restrict__ cntI, const int* __restrict__ cpI,
                     const uint8_t* __restrict__ TU, const uint8_t* __restrict__ TI,
                     uint8_t* __restrict__ dU, uint8_t* __restrict__ dI,
                     uint16_t* __restrict__ sumU, uint16_t* __restrict__ sumI,
                     const float* __restrict__ baseU, const float* __restrict__ baseI,
                     uint16_t* __restrict__ wrU, uint16_t* __restrict__ wrI) {
  int lane = threadIdx.x & 63;
  int g = lane >> 4, l15 = lane & 15;
  int w = (blockIdx.x * blockDim.x + threadIdx.x) >> 6;
  int r = w * 4 + g;
  const int* cnt; const int* cp; const uint8_t *T, *Rt;
  uint8_t* D; uint16_t* Sum; const float* base; uint16_t* wr; int row, cap;
  if (r < NU) {
    row = r; cnt = cntU; cp = cpU; T = TI; Rt = TU; cap = CAP_U;
    D = dU; Sum = sumU; base = baseU; wr = wrU;
  } else {
    row = r - NU; cnt = cntI; cp = cpI; T = TU; Rt = TI; cap = CAP_I;
    D = dI; Sum = sumI; base = baseI; wr = wrI;
  }
  // row-side logit vector (128x-scaled fp8 sums -> float), dword1 of own row
  uint32_t rv = *(const uint32_t*)(Rt + ((size_t)row << 7) + l15 * 8 + 4);
  f32x4 rr = fp8_to4(rv);
  int p0 = row * cap, p1 = p0 + cnt[row];
  f32x4 acc = {0.f, 0.f, 0.f, 0.f};
  int p = p0;
  for (; p + 4 <= p1; p += 4) {
    int c0 = cp[p], c1 = cp[p + 1], c2 = cp[p + 2], c3 = cp[p + 3];
    uint2 sg0 = *(const uint2*)(T + ((size_t)(uint32_t)(c0 & 0x1FFFF) << 7) + l15 * 8);
    uint2 sg1 = *(const uint2*)(T + ((size_t)(uint32_t)(c1 & 0x1FFFF) << 7) + l15 * 8);
    uint2 sg2 = *(const uint2*)(T + ((size_t)(uint32_t)(c2 & 0x1FFFF) << 7) + l15 * 8);
    uint2 sg3 = *(const uint2*)(T + ((size_t)(uint32_t)(c3 & 0x1FFFF) << 7) + l15 * 8);
    f32x4 g0 = fp8_to4(sg0.y), g1 = fp8_to4(sg1.y);
    f32x4 g2 = fp8_to4(sg2.y), g3 = fp8_to4(sg3.y);
    float d0 = rr[0] * g0[0] + rr[1] * g0[1] + rr[2] * g0[2] + rr[3] * g0[3];
    float d1 = rr[0] * g1[0] + rr[1] * g1[1] + rr[2] * g1[2] + rr[3] * g1[3];
    float d2 = rr[0] * g2[0] + rr[1] * g2[1] + rr[2] * g2[2] + rr[3] * g2[3];
    float d3 = rr[0] * g3[0] + rr[1] * g3[1] + rr[2] * g3[2] + rr[3] * g3[3];
#pragma unroll
    for (int o = 1; o < 16; o <<= 1) {
      d0 += __shfl_xor(d0, o, 16);
      d1 += __shfl_xor(d1, o, 16);
      d2 += __shfl_xor(d2, o, 16);
      d3 += __shfl_xor(d3, o, 16);
    }
    float a0 = (float)(((uint32_t)c0) >> 21) * AV_DEC / (1.0f + __expf(-d0 * EL_DESCALE));
    float a1 = (float)(((uint32_t)c1) >> 21) * AV_DEC / (1.0f + __expf(-d1 * EL_DESCALE));
    float a2 = (float)(((uint32_t)c2) >> 21) * AV_DEC / (1.0f + __expf(-d2 * EL_DESCALE));
    float a3 = (float)(((uint32_t)c3) >> 21) * AV_DEC / (1.0f + __expf(-d3 * EL_DESCALE));
    if (l15 == 0) {
      wr[p] = (uint16_t)(a0 * AUG_ENC + 0.5f);
      wr[p + 1] = (uint16_t)(a1 * AUG_ENC + 0.5f);
      wr[p + 2] = (uint16_t)(a2 * AUG_ENC + 0.5f);
      wr[p + 3] = (uint16_t)(a3 * AUG_ENC + 0.5f);
    }
    float v0 = a0 * (float)((c0 >> 19) & 1);
    float v1 = a1 * (float)((c1 >> 19) & 1);
    float v2 = a2 * (float)((c2 >> 19) & 1);
    float v3 = a3 * (float)((c3 >> 19) & 1);
    f32x4 f0 = fp8_to4(sg0.x), f1 = fp8_to4(sg1.x);
    f32x4 f2 = fp8_to4(sg2.x), f3 = fp8_to4(sg3.x);
#pragma unroll
    for (int k = 0; k < 4; ++k)
      acc[k] += (v0 * f0[k] + v1 * f1[k]) + (v2 * f2[k] + v3 * f3[k]);
  }
  for (; p < p1; ++p) {
    int c0 = cp[p];
    uint2 sg0 = *(const uint2*)(T + ((size_t)(uint32_t)(c0 & 0x1FFFF) << 7) + l15 * 8);
    f32x4 g0 = fp8_to4(sg0.y);
    float d0 = rr[0] * g0[0] + rr[1] * g0[1] + rr[2] * g0[2] + rr[3] * g0[3];
#pragma unroll
    for (int o = 1; o < 16; o <<= 1) d0 += __shfl_xor(d0, o, 16);
    float a0 = (float)(((uint32_t)c0) >> 21) * AV_DEC / (1.0f + __expf(-d0 * EL_DESCALE));
    if (l15 == 0) wr[p] = (uint16_t)(a0 * AUG_ENC + 0.5f);
    float v0 = a0 * (float)((c0 >> 19) & 1);
    f32x4 f0 = fp8_to4(sg0.x);
#pragma unroll
    for (int k = 0; k < 4; ++k) acc[k] += v0 * f0[k];
  }
  size_t idx = (size_t)row * DD + l15 * 4;
  *(uint32_t*)(D + idx) = pack4_fp8(acc[0] * (4.0f / 3.0f), acc[1] * (4.0f / 3.0f),
                                    acc[2] * (4.0f / 3.0f), acc[3] * (4.0f / 3.0f));
  float4 b4 = *(const float4*)(base + idx);
  ushort4 s;
  s.x = f2bf(b4.x + acc[0] * SPMM_DESCALE);
  s.y = f2bf(b4.y + acc[1] * SPMM_DESCALE);
  s.z = f2bf(b4.z + acc[2] * SPMM_DESCALE);
  s.w = f2bf(b4.w + acc[3] * SPMM_DESCALE);
  *(ushort4*)(Sum + idx) = s;
}

// base tables fp32 -> fp8(x128): COMPACT 64B-row copies (prop0-L0 gathers)
// AND the interleaved tables' dword0 slots (spmm_aug gathers), plus fused
// L2-reg sum-of-squares (Eu0,Ev0,Eb).
__global__ void cvt2_fp8_kernel(const float4* __restrict__ a, int na4,
                                uint32_t* __restrict__ oca, uint32_t* __restrict__ oia,
                                const float4* __restrict__ b, int nb4,
                                uint32_t* __restrict__ ocb, uint32_t* __restrict__ oib,
                                const float4* __restrict__ c, int nc4,
                                float* __restrict__ acc) {
  __shared__ float red[256];
  int total = na4 + nb4 + nc4;
  float s = 0.f;
  for (int i = blockIdx.x * blockDim.x + threadIdx.x; i < total; i += gridDim.x * blockDim.x) {
    float4 v = (i < na4) ? a[i] : (i < na4 + nb4) ? b[i - na4] : c[i - na4 - nb4];
    s += v.x * v.x + v.y * v.y + v.z * v.z + v.w * v.w;
    if (i < na4 + nb4) {
      uint32_t w = pack4_fp8(v.x * FP8_SCALE, v.y * FP8_SCALE, v.z * FP8_SCALE, v.w * FP8_SCALE);
      if (i < na4) {
        oca[i] = w;
        oia[((i >> 4) << 5) + ((i & 15) << 1)] = w;
      } else {
        int j = i - na4;
        ocb[j] = w;
        oib[((j >> 4) << 5) + ((j & 15) << 1)] = w;
      }
    }
  }
  red[threadIdx.x] = s;
  __syncthreads();
  for (int st = 128; st > 0; st >>= 1) {
    if (threadIdx.x < st) red[threadIdx.x] += red[threadIdx.x + st];
    __syncthreads();
  }
  if (threadIdx.x == 0) atomicAdd(&acc[7], red[0]);
}

// gather both Z row sets; PRE-SCALE by LOG2E5 so PCL's MFMA emits
// already-log2-scaled logits
__global__ void gather2_rows_kernel(const uint16_t* __restrict__ Z16u, const int* __restrict__ uids,
                                    uint16_t* __restrict__ ou,
                                    const uint16_t* __restrict__ Z16i, const int* __restrict__ iids,
                                    uint16_t* __restrict__ oi) {
  int b = blockIdx.x, lane = threadIdx.x;
  if (b < BATCH)
    ou[(size_t)b * 64 + lane] = f2bf(bf2f(Z16u[(size_t)uids[b] * 64 + lane]) * LOG2E5);
  else {
    int bb = b - BATCH;
    oi[(size_t)bb * 64 + lane] = f2bf(bf2f(Z16i[(size_t)iids[bb] * 64 + lane]) * LOG2E5);
  }
}

// PCL denominator: S[m] += sum_n exp2(dot(Zg_scaled[m],E[n])), bf16 MFMA.
// v12: round-9 grid (dim3(128,16), best measured: 113us/43%occ; r10/r11
// grid-size probes both worse) + LDS-staged B tile: all 4 waves of a block
// consumed the SAME 2KB n-tile from L2 every iter (4x redundant traffic,
// each wave stalled on its own L2/L3 round-trip; MfmaUtil 13%). Now one
// cooperative 2KB copy per iter, double-buffered, XOR-swizzled vs the
// 128B-stride bank pattern, global load for tile k+1 issued before compute
// on tile k so HBM/L3 latency hides under 8 MFMA + 16 exp2.
__global__ __launch_bounds__(256)
void pcl_mfma9_kernel(const uint16_t* __restrict__ Zgu, const uint16_t* __restrict__ E16u,
                      int NTu, float* __restrict__ Su,
                      const uint16_t* __restrict__ Zgi, const uint16_t* __restrict__ E16i,
                      int NTi, float* __restrict__ Si) {
  __shared__ uint8_t ldsb[2][2048];
  int lane = threadIdx.x & 63;
  int wave = threadIdx.x >> 6;
  int quad = lane >> 4, l15 = lane & 15;
  bool isU = blockIdx.y < 8;
  const uint16_t* Zg = isU ? Zgu : Zgi;
  const uint16_t* E16 = isU ? E16u : E16i;
  int NT = isU ? NTu : NTi;
  float* S = isU ? Su : Si;
  const int SPL = 128;
  int mt0 = (((int)blockIdx.y & 7) * 4 + wave) * 4;   // 4 consecutive m-tiles/wave
  bf16x8 a0[4], a1[4];
#pragma unroll
  for (int i = 0; i < 4; ++i) {
    const uint16_t* ar = Zg + (size_t)((mt0 + i) * 16 + l15) * 64 + quad * 8;
    a0[i] = *(const bf16x8*)ar;
    a1[i] = *(const bf16x8*)(ar + 32);
  }
  int t = threadIdx.x;
  // swizzle: XOR row bits (byte>>7 & 7) into bits 4..6 (16B-slot index)
  int wof = (t * 8) ^ (((t >> 4) & 7) << 4);
  int rof0 = (l15 * 128 + quad * 16) ^ ((l15 & 7) << 4);
  int rof1 = (l15 * 128 + quad * 16 + 64) ^ ((l15 & 7) << 4);
  f32x4 rs[4] = {};
  int nt = blockIdx.x;
  {
    uint2 g0 = make_uint2(0u, 0u);
    if (nt < NT)
      g0 = *(const uint2*)((const uint8_t*)E16 + (size_t)nt * 2048 + t * 8);
    *(uint2*)(&ldsb[0][wof]) = g0;
  }
  __syncthreads();
  int cur = 0;
  while (nt < NT) {
    int nn = nt + SPL;
    uint2 gn = make_uint2(0u, 0u);
    if (nn < NT)
      gn = *(const uint2*)((const uint8_t*)E16 + (size_t)nn * 2048 + t * 8);
    bf16x8 b0 = *(const bf16x8*)(&ldsb[cur][rof0]);
    bf16x8 b1 = *(const bf16x8*)(&ldsb[cur][rof1]);
#pragma unroll
    for (int i = 0; i < 4; ++i) {
      f32x4 c = {0.f, 0.f, 0.f, 0.f};
      c = __builtin_amdgcn_mfma_f32_16x16x32_bf16(a0[i], b0, c, 0, 0, 0);
      c = __builtin_amdgcn_mfma_f32_16x16x32_bf16(a1[i], b1, c, 0, 0, 0);
#pragma unroll
      for (int r = 0; r < 4; ++r) rs[i][r] += __builtin_amdgcn_exp2f(c[r]);
    }
    *(uint2*)(&ldsb[cur ^ 1][wof]) = gn;
    __syncthreads();
    cur ^= 1; nt = nn;
  }
#pragma unroll
  for (int off = 8; off > 0; off >>= 1) {
#pragma unroll
    for (int i = 0; i < 4; ++i)
#pragma unroll
      for (int r = 0; r < 4; ++r) rs[i][r] += __shfl_down(rs[i][r], off, 16);
  }
  if (l15 == 0) {
#pragma unroll
    for (int i = 0; i < 4; ++i)
#pragma unroll
      for (int r = 0; r < 4; ++r)
        atomicAdd(&S[(mt0 + i) * 16 + quad * 4 + r], rs[i][r]);
  }
}

__global__ void bpr_kernel(const uint16_t* __restrict__ E16u, const uint16_t* __restrict__ E16i,
                           const int* __restrict__ uids, const int* __restrict__ pos,
                           const int* __restrict__ neg, float* __restrict__ ps,
                           float* __restrict__ acc) {
  int lane = threadIdx.x & 63;
  int b = (blockIdx.x * blockDim.x + threadIdx.x) >> 6;
  if (b >= BATCH) return;
  float u = bf2f(E16u[(size_t)uids[b] * DD + lane]);
  float p = u * bf2f(E16i[(size_t)pos[b] * DD + lane]);
  float n = u * bf2f(E16i[(size_t)neg[b] * DD + lane]);
#pragma unroll
  for (int off = 32; off > 0; off >>= 1) { p += __shfl_down(p, off); n += __shfl_down(n, off); }
  if (lane == 0) {
    ps[b] = p;
    float x = p - n;
    atomicAdd(&acc[0], logf(1.0f / (1.0f + __expf(-x))));
  }
}

__global__ void minmax_kernel(const float* __restrict__ ps, float* __restrict__ mm) {
  __shared__ float smn[256], smx[256];
  int tid = threadIdx.x;
  float mn = 3.0e38f, mx = -3.0e38f;
  for (int i = tid; i < BATCH; i += 256) { float v = ps[i]; mn = fminf(mn, v); mx = fmaxf(mx, v); }
  smn[tid] = mn; smx[tid] = mx;
  __syncthreads();
  for (int s = 128; s > 0; s >>= 1) {
    if (tid < s) { smn[tid] = fminf(smn[tid], smn[tid + s]); smx[tid] = fmaxf(smx[tid], smx[tid + s]); }
    __syncthreads();
  }
  if (tid == 0) { mm[0] = smn[0]; mm[1] = smx[0]; }
}

__global__ void bcl_kernel(const uint16_t* __restrict__ E16u, const uint16_t* __restrict__ E16i,
                           const float* __restrict__ Eb, const int* __restrict__ uids,
                           const int* __restrict__ pos, const float* __restrict__ ps,
                           const float* __restrict__ mm, float* __restrict__ acc) {
  int lane = threadIdx.x & 63;
  int b = (blockIdx.x * blockDim.x + threadIdx.x) >> 6;
  if (b >= BATCH) return;
  float wgt = (ps[b] - mm[0]) / (mm[1] - mm[0] + 1e-9f);
  int rel = (int)(wgt * 10.0f);
  rel = rel < 0 ? 0 : (rel > 9 ? 9 : rel);
  float x = bf2f(E16u[(size_t)uids[b] * DD + lane]) * bf2f(E16i[(size_t)pos[b] * DD + lane]);
  float el = 1.0f / (1.0f + __expf(-x));
  float sneg = 0.f, spos = 0.f;
  for (int k = 0; k < NBK; ++k) {
    float d = el * Eb[k * DD + lane];
#pragma unroll
    for (int off = 32; off > 0; off >>= 1) d += __shfl_down(d, off);
    if (lane == 0) { if (k == rel) spos = d; else sneg += d; }
  }
  if (lane == 0) {
    atomicAdd(&acc[5], sneg * 0.1f);
    atomicAdd(&acc[6], spos);
  }
}

__global__ void pclpos2_kernel(const uint16_t* __restrict__ Z16u, const uint16_t* __restrict__ E16u,
                               const int* __restrict__ uids,
                               const uint16_t* __restrict__ Z16i, const uint16_t* __restrict__ E16i,
                               const int* __restrict__ iids, float* __restrict__ acc) {
  int lane = threadIdx.x & 63;
  int b = (blockIdx.x * blockDim.x + threadIdx.x) >> 6;
  if (b >= 2 * BATCH) return;
  const uint16_t *Z, *E; const int* ids; int idx, bb;
  if (b < BATCH) { Z = Z16u; E = E16u; ids = uids; idx = 3; bb = b; }
  else { Z = Z16i; E = E16i; ids = iids; idx = 4; bb = b - BATCH; }
  size_t r = (size_t)ids[bb] * DD + lane;
  float p = bf2f(Z[r]) * bf2f(E[r]);
#pragma unroll
  for (int off = 32; off > 0; off >>= 1) p += __shfl_down(p, off);
  if (lane == 0) {
    float x = p * 5.0f;
    x = fminf(5.0f, fmaxf(-5.0f, x));
    atomicAdd(&acc[idx], x);
  }
}

__global__ void finalize_kernel(const float* __restrict__ Su, const float* __restrict__ Si,
                                const float* __restrict__ acc, float* __restrict__ out) {
  __shared__ float r1[256], r2[256];
  int tid = threadIdx.x;
  float su = 0.f, si = 0.f;
  for (int b = tid; b < BATCH; b += 256) {
    su += logf(Su[b] + 1e-8f);
    si += logf(Si[b] + 1e-8f);
  }
  r1[tid] = su; r2[tid] = si;
  __syncthreads();
  for (int s = 128; s > 0; s >>= 1) {
    if (tid < s) { r1[tid] += r1[tid + s]; r2[tid] += r2[tid + s]; }
    __syncthreads();
  }
  if (tid == 0) {
    const float inv = 1.0f / (float)BATCH;
    float neg_s = (r1[0] + r2[0]) * inv;
    float pos_s = (acc[3] + acc[4]) * inv;
    float pcl = neg_s - pos_s;
    float bpr = -acc[0] * inv;
    float bcl = (acc[5] - acc[6]) * inv;
    float reg = 1e-7f * acc[7];
    float loss = bpr + 0.2f * pcl + 0.2f * bcl + reg;
    out[0] = loss; out[1] = bpr; out[2] = 0.2f * pcl; out[3] = 0.2f * bcl;
  }
}

extern "C" void kernel_launch(void* const* d_in, const int* in_sizes, int n_in,
                              void* d_out, int out_size, void* d_ws, size_t ws_size,
                              hipStream_t stream) {
  (void)in_sizes; (void)n_in; (void)out_size; (void)ws_size;
  const float* Eu0 = (const float*)d_in[0];
  const float* Ev0 = (const float*)d_in[1];
  const float* Eb  = (const float*)d_in[2];
  const float* av  = (const float*)d_in[3];
  const int* rows  = (const int*)d_in[4];
  const int* cols  = (const int*)d_in[5];
  const int* uids  = (const int*)d_in[6];
  const int* iids  = (const int*)d_in[7];
  const int* pos   = (const int*)d_in[8];
  const int* neg   = (const int*)d_in[9];
  float* out = (float*)d_out;

  float* w = (float*)d_ws;
  size_t o = 0;
  float* ps  = w + o; o += BATCH;
  float* Su  = w + o; o += BATCH;
  float* Si  = w + o; o += BATCH;
  float* acc = w + o; o += 16;
  float* mm  = w + o; o += 2;
  // bf16 running-sum tables + gathered Z rows + u16 aug streams
  uint16_t* hp = (uint16_t*)(w + o);
  uint16_t* E16u = hp; hp += (size_t)NU * DD;
  uint16_t* E16i = hp; hp += (size_t)NI * DD;
  uint16_t* Z16u = hp; hp += (size_t)NU * DD;
  uint16_t* Z16i = hp; hp += (size_t)NI * DD;
  uint16_t* Zgu  = hp; hp += (size_t)BATCH * DD;
  uint16_t* Zgi  = hp; hp += (size_t)BATCH * DD;
  uint16_t* augU = hp; hp += (size_t)NU * CAP_U + 64;  // aug weights (u16, bucket order)
  uint16_t* augI = hp; hp += (size_t)NI * CAP_I + 64;
  // fp8 tables
  uint8_t* bp = (uint8_t*)hp;
  uint8_t* TU  = bp; bp += (size_t)NU * 128;    // interleaved {base, sum} 128B rows
  uint8_t* TI  = bp; bp += (size_t)NI * 128;
  uint8_t* E0u8 = bp; bp += (size_t)NU * DD;    // compact base (prop0-L0 gathers)
  uint8_t* E0v8 = bp; bp += (size_t)NI * DD;
  uint8_t* d8U = bp; bp += (size_t)NU * DD;     // layer0 outs (fp8, 128x, plain 64B)
  uint8_t* d8I = bp; bp += (size_t)NI * DD;
  uint8_t* mask8 = bp; bp += NE;
  // int region (8B aligned): fill counters + bucket cp arrays
  int* ip = (int*)(((uintptr_t)bp + 7) & ~(uintptr_t)7);
  int* cntU = ip; ip += NU;
  int* cntI = ip; ip += NI;
  int* cpU = ip; ip += (size_t)NU * CAP_U + 64;
  int* cpI = ip; ip += (size_t)NI * CAP_I + 64;

  // key chain: key(42) = (0,42); fold_in(k,d) = threefry2x32(k, [0,d])
  uint32_t bk[2][2];
  tf2x32(0u, 42u, 0u, 0u, bk[0][0], bk[0][1]);
  tf2x32(0u, 42u, 0u, 1u, bk[1][0], bk[1][1]);
  Keys8 K;
  for (int p = 0; p < 2; ++p)
    for (int l = 0; l < 2; ++l) {
      tf2x32(bk[p][0], bk[p][1], 0u, (uint32_t)(2 * l),     K.k[p * 2 + l][0], K.k[p * 2 + l][1]);
      tf2x32(bk[p][0], bk[p][1], 0u, (uint32_t)(2 * l + 1), K.k[4 + p * 2 + l][0], K.k[4 + p * 2 + l][1]);
    }

  // acc must be zero before cvt2 (fused sumsq accumulates acc[7])
  (void)hipMemsetAsync(ps, 0, (3 * BATCH + 18) * sizeof(float), stream);
  cvt2_fp8_kernel<<<2048, 256, 0, stream>>>(
      (const float4*)Eu0, NU * DD / 4, (uint32_t*)E0u8, (uint32_t*)TU,
      (const float4*)Ev0, NI * DD / 4, (uint32_t*)E0v8, (uint32_t*)TI,
      (const float4*)Eb, NBK * DD / 4, acc);
  mask_kernel<<<(NE / 2 + 255) / 256, 256, 0, stream>>>(mask8, K);
  (void)hipMemsetAsync(cntU, 0, (size_t)(NU + NI) * sizeof(int), stream);
  // bucket scatter (hist + scan deleted in v8)
  scatter_kernel<<<NCHUNK * NSLICE, 256, 0, stream>>>(rows, cols, mask8, av,
                                                      cntU, cntI, cpU, cpI);

  const int SPB = (NU + NI) / 16;   // 4 rows/wave, 4 waves/block -> 9375 blocks

  // ---- propagation 0 (mask bits 17/18, packed av weights; compact tables) ----
  spmm_layer_kernel<<<SPB, 256, 0, stream>>>(cntU, cpU, cntI, cpI, nullptr, nullptr, 17,
                                             E0v8, E0u8, d8U, d8I,
                                             E16u, E16i, Eu0, Ev0, nullptr, nullptr);
  spmm_layer_kernel<<<SPB, 256, 0, stream>>>(cntU, cpU, cntI, cpI, nullptr, nullptr, 18,
                                             d8I, d8U, nullptr, nullptr,
                                             E16u, E16i, nullptr, nullptr, TU, TI);

  // ---- propagation 1 layer 0 + fused edge-logit (bit 19; writes augU/augI) ----
  spmm_aug_kernel<<<SPB, 256, 0, stream>>>(cntU, cpU, cntI, cpI, TU, TI,
                                           d8U, d8I, Z16u, Z16i, Eu0, Ev0,
                                           augU, augI);
  // ---- propagation 1 layer 1 (bit 20, sequential u16 aug weights) ----
  spmm_layer_kernel<<<SPB, 256, 0, stream>>>(cntU, cpU, cntI, cpI, augU, augI, 20,
                                             d8I, d8U, nullptr, nullptr,
                                             Z16u, Z16i, nullptr, nullptr, nullptr, nullptr);

  gather2_rows_kernel<<<2 * BATCH, 64, 0, stream>>>(Z16u, uids, Zgu, Z16i, iids, Zgi);

  bpr_kernel<<<BATCH / 4, 256, 0, stream>>>(E16u, E16i, uids, pos, neg, ps, acc);
  minmax_kernel<<<1, 256, 0, stream>>>(ps, mm);
  bcl_kernel<<<BATCH / 4, 256, 0, stream>>>(E16u, E16i, Eb, uids, pos, ps, mm, acc);

  // PCL denominators: round-9 grid (best measured) + LDS-staged B tiles
  pcl_mfma9_kernel<<<dim3(128, 16), 256, 0, stream>>>(Zgu, E16u, NU / 16, Su,
                                                      Zgi, E16i, NI / 16, Si);

  pclpos2_kernel<<<2 * BATCH / 4, 256, 0, stream>>>(Z16u, E16u, uids, Z16i, E16i, iids, acc);

  finalize_kernel<<<1, 256, 0, stream>>>(Su, Si, acc, out);
}

// Round 13
// 673.040 us; speedup vs baseline: 1.1064x; 1.0320x over previous
//
#include <hip/hip_runtime.h>
#include <stdint.h>

#define NU 100000
#define NI 50000
#define NBK 10
#define DD 64
#define NE 1000000
#define BATCH 2048
#define NSLICE 8
#define USLICE ((NU + NSLICE - 1) / NSLICE)   // 12500
#define ISLICE ((NI + NSLICE - 1) / NSLICE)   // 6250
#define NCHUNK 512
#define EPC ((NE + NCHUNK - 1) / NCHUNK)      // 1954
// row bucket capacities, LINE-ALIGNED (v13): 32 ints = 128B (U), 64 ints =
// 256B (I). Poisson(10): P(deg>32) ~ 7e-9/row; Poisson(20): >64 is ~10sigma.
// Aligned buckets stop typical ~40-80B fills straddling an extra 64B line.
#define CAP_U 32
#define CAP_I 64
// fp8 storage scale: embeddings ~0.01 are subnormal in e4m3; x128 -> normal.
// Combined descale: (4/3 dropout) / 128 = 1/96.
#define FP8_SCALE 128.0f
#define SPMM_DESCALE (1.0f / 96.0f)
#define EL_DESCALE (1.0f / 16384.0f)   // edge-logit dot of two 128x fp8 tables
#define LOG2E5 7.2134752f              // 5*log2(e): exp(5x) = 2^(x*LOG2E5)
// av in [0, 0.05): 11-bit fixed point in cp bits 21..31 (cp entry = ONE int:
// col 17b | mask 4b @17 | av 11b @21).
#define AV_ENC 40960.0f                // 2^11 / 0.05
#define AV_DEC (0.05f / 2048.0f)
// aug weights stored u16 fixed-point (rel err ~2e-5, << fp8 table error)
#define AUG_ENC (65535.0f / 0.05f)
#define AUG_DEC (0.05f / 65535.0f)

typedef __bf16 bf16x8 __attribute__((ext_vector_type(8)));
typedef float f32x4 __attribute__((ext_vector_type(4)));
typedef float f32x2 __attribute__((ext_vector_type(2)));

struct Keys8 { uint32_t k[8][2]; };

// ---------------- threefry2x32 (JAX-compatible, 20 rounds) ----------------
__host__ __device__ inline void tf2x32(uint32_t k0, uint32_t k1, uint32_t x0, uint32_t x1,
                                       uint32_t& o0, uint32_t& o1) {
  uint32_t ks0 = k0, ks1 = k1, ks2 = k0 ^ k1 ^ 0x1BD11BDAu;
  x0 += ks0; x1 += ks1;
#define TFR(r) { x0 += x1; x1 = (x1 << (r)) | (x1 >> (32 - (r))); x1 ^= x0; }
  TFR(13) TFR(15) TFR(26) TFR(6)   x0 += ks1; x1 += ks2 + 1u;
  TFR(17) TFR(29) TFR(16) TFR(24)  x0 += ks2; x1 += ks0 + 2u;
  TFR(13) TFR(15) TFR(26) TFR(6)   x0 += ks0; x1 += ks1 + 3u;
  TFR(17) TFR(29) TFR(16) TFR(24)  x0 += ks1; x1 += ks2 + 4u;
  TFR(13) TFR(15) TFR(26) TFR(6)   x0 += ks2; x1 += ks0 + 5u;
#undef TFR
  o0 = x0; o1 = x1;
}

__device__ inline uint16_t f2bf(float f) {
  uint32_t u = __float_as_uint(f);
  return (uint16_t)((u + 0x7fffu + ((u >> 16) & 1u)) >> 16);   // RNE
}
__device__ inline float bf2f(uint16_t u) {
  return __uint_as_float(((uint32_t)u) << 16);
}

// ---- fp8 e4m3 (OCP) helpers ----
template <int SEL>
__device__ inline float fp8_sel(uint32_t w) {
#if __has_builtin(__builtin_amdgcn_cvt_f32_fp8)
  return __builtin_amdgcn_cvt_f32_fp8((int)w, SEL);
#else
  uint32_t b = (w >> (8 * SEL)) & 0xFFu;
  uint32_t s = b >> 7, e = (b >> 3) & 0xF, m = b & 7;
  float v = (e == 0) ? (float)m * (1.0f / 512.0f)
                     : __uint_as_float(((e + 120) << 23) | (m << 20));
  return s ? -v : v;
#endif
}
// packed decode: one dword of 4 fp8 -> f32x4 via 2x v_cvt_pk_f32_fp8
__device__ inline f32x4 fp8_to4(uint32_t w) {
#if __has_builtin(__builtin_amdgcn_cvt_pk_f32_fp8)
  f32x2 lo = __builtin_amdgcn_cvt_pk_f32_fp8((int)w, false);
  f32x2 hi = __builtin_amdgcn_cvt_pk_f32_fp8((int)w, true);
  f32x4 r; r[0] = lo[0]; r[1] = lo[1]; r[2] = hi[0]; r[3] = hi[1];
  return r;
#else
  f32x4 r; r[0] = fp8_sel<0>(w); r[1] = fp8_sel<1>(w);
  r[2] = fp8_sel<2>(w); r[3] = fp8_sel<3>(w);
  return r;
#endif
}
__device__ inline uint32_t f32_to_fp8(float f) {
#if __has_builtin(__builtin_amdgcn_cvt_pk_fp8_f32)
  return (uint32_t)__builtin_amdgcn_cvt_pk_fp8_f32(f, f, 0, false) & 0xFFu;
#else
  uint32_t s = (__float_as_uint(f) >> 31) << 7;
  float a = fabsf(f);
  a = fminf(a, 448.0f);
  if (a < 0.015625f) {
    uint32_t m = (uint32_t)(a * 512.0f + 0.5f);
    return s | m;
  }
  int ex; float fr = frexpf(a, &ex);
  uint32_t q = (uint32_t)(fr * 16.0f + 0.5f);
  int E = ex + 6;
  if (q == 16) { q = 8; E += 1; }
  if (E > 15) { E = 15; q = 14; }
  if (E == 15 && q == 15) q = 14;
  return s | ((uint32_t)E << 3) | (q - 8);
#endif
}
__device__ inline uint32_t pack4_fp8(float a, float b, float c, float d) {
  return f32_to_fp8(a) | (f32_to_fp8(b) << 8) | (f32_to_fp8(c) << 16) | (f32_to_fp8(d) << 24);
}

#define CVTB 2048
#define MASKB ((NE / 2 + 255) / 256)          // 1954
#define ZEROB ((NU + NI + 255) / 256)         // 586

// v13 fused prep: [0,CVTB) fp32->fp8 conversions + L2-reg sumsq;
// [CVTB, CVTB+MASKB) dropout masks; rest: zero the cnt arrays.
__global__ void prep_kernel(const float4* __restrict__ a, int na4,
                            uint32_t* __restrict__ oca, uint32_t* __restrict__ oia,
                            const float4* __restrict__ b, int nb4,
                            uint32_t* __restrict__ ocb, uint32_t* __restrict__ oib,
                            const float4* __restrict__ c, int nc4,
                            float* __restrict__ acc,
                            uint8_t* __restrict__ mask, Keys8 K,
                            int* __restrict__ cnt) {
  int bid = blockIdx.x, tid = threadIdx.x;
  if (bid < CVTB) {
    __shared__ float red[256];
    int total = na4 + nb4 + nc4;
    float s = 0.f;
    for (int i = bid * 256 + tid; i < total; i += CVTB * 256) {
      float4 v = (i < na4) ? a[i] : (i < na4 + nb4) ? b[i - na4] : c[i - na4 - nb4];
      s += v.x * v.x + v.y * v.y + v.z * v.z + v.w * v.w;
      if (i < na4 + nb4) {
        uint32_t w = pack4_fp8(v.x * FP8_SCALE, v.y * FP8_SCALE, v.z * FP8_SCALE, v.w * FP8_SCALE);
        if (i < na4) {
          oca[i] = w;
          oia[((i >> 4) << 5) + ((i & 15) << 1)] = w;
        } else {
          int j = i - na4;
          ocb[j] = w;
          oib[((j >> 4) << 5) + ((j & 15) << 1)] = w;
        }
      }
    }
    red[tid] = s;
    __syncthreads();
    for (int st = 128; st > 0; st >>= 1) {
      if (tid < st) red[tid] += red[tid + st];
      __syncthreads();
    }
    if (tid == 0) atomicAdd(&acc[7], red[0]);
  } else if (bid < CVTB + MASKB) {
    const int half = NE / 2;
    int e = (bid - CVTB) * 256 + tid;
    if (e >= half) return;
    uint32_t mlo = 0, mhi = 0;
#pragma unroll
    for (int j = 0; j < 8; ++j) {
      uint32_t o0, o1;
      tf2x32(K.k[j][0], K.k[j][1], (uint32_t)e, (uint32_t)(e + half), o0, o1);
      float u0 = __uint_as_float((o0 >> 9) | 0x3f800000u) - 1.0f;
      float u1 = __uint_as_float((o1 >> 9) | 0x3f800000u) - 1.0f;
      mlo |= (u0 < 0.75f ? 1u : 0u) << j;
      mhi |= (u1 < 0.75f ? 1u : 0u) << j;
    }
    mask[e] = (uint8_t)mlo;
    mask[e + half] = (uint8_t)mhi;
  } else {
    int i = (bid - CVTB - MASKB) * 256 + tid;
    if (i < NU + NI) cnt[i] = 0;
  }
}

// XCD-sliced bucket scatter (slice = blockIdx&7; L2-local atomics per round-2
// measurement). Fixed-capacity LINE-ALIGNED row buckets self-allocated by
// atomicAdd. ~90-104us across 7 structural variants -> atomic/latency floor.
__global__ __launch_bounds__(256)
void scatter_kernel(const int* __restrict__ rows, const int* __restrict__ cols,
                    const uint8_t* __restrict__ mask, const float* __restrict__ av,
                    int* __restrict__ cntU, int* __restrict__ cntI,
                    int* __restrict__ cpU, int* __restrict__ cpI) {
  int slice = blockIdx.x & 7;
  int chunk = blockIdx.x >> 3;
  int base = chunk * EPC;
  int end = base + EPC; if (end > NE) end = NE;
  for (int e = base + threadIdx.x; e < end; e += 256) {
    int r = __builtin_nontemporal_load(rows + e);
    int c = __builtin_nontemporal_load(cols + e);
    uint32_t m = __builtin_nontemporal_load(mask + e);
    float a = __builtin_nontemporal_load(av + e);
    uint32_t q = (uint32_t)(a * AV_ENC + 0.5f);
    if (q > 2047u) q = 2047u;
    uint32_t qb = q << 21;
    if (r / USLICE == slice) {
      int old = atomicAdd(&cntU[r], 1);
      cpU[(r << 5) + old] = (int)((uint32_t)c | ((m & 0xFu) << 17) | qb);
    }
    if (c / ISLICE == slice) {
      int old = atomicAdd(&cntI[c], 1);
      cpI[(c << 6) + old] = (int)((uint32_t)r | (((m >> 4) & 0xFu) << 17) | qb);
    }
  }
}

// weight: rdw!=null -> sequential u16 aug stream (prop1-L1); else decode the
// 11-bit packed av (prop0, no memory access).
__device__ inline float cp_weight(int cc, const uint16_t* __restrict__ rdw, int p, int shift) {
  float mb = (float)((cc >> shift) & 1);
  if (rdw) return (float)rdw[p] * AUG_DEC * mb;
  return (float)(((uint32_t)cc) >> 21) * AV_DEC * mb;
}

// merged U+I gather-reduce SpMM, sub-wave layout: wave = 4 rows x 16 lanes,
// lane covers 4 dims via one dword fp8 load. Zero-weight entries redirect
// their gather to row 0 (branchless; row 0 becomes L1/L2-hot).
__global__ __launch_bounds__(256)
void spmm_layer_kernel(const int* __restrict__ cntU, const int* __restrict__ cpU,
                       const int* __restrict__ cntI, const int* __restrict__ cpI,
                       const uint16_t* __restrict__ rdU, const uint16_t* __restrict__ rdI,
                       int shift,
                       const uint8_t* __restrict__ SU, const uint8_t* __restrict__ SI,
                       uint8_t* __restrict__ dU, uint8_t* __restrict__ dI,
                       uint16_t* __restrict__ sumU, uint16_t* __restrict__ sumI,
                       const float* __restrict__ baseU, const float* __restrict__ baseI,
                       uint8_t* __restrict__ s8U, uint8_t* __restrict__ s8I) {
  int lane = threadIdx.x & 63;
  int g = lane >> 4, l15 = lane & 15;
  int w = (blockIdx.x * blockDim.x + threadIdx.x) >> 6;
  int r = w * 4 + g;                       // NU%4==0 -> wave never straddles U/I
  const int* cnt; const int* cp; const uint8_t* S; const uint16_t* rdw;
  uint8_t* D; uint16_t* Sum; const float* base; uint8_t* S8; int row, cap;
  if (r < NU) {
    row = r; cnt = cntU; cp = cpU; S = SU; rdw = rdU; cap = CAP_U;
    D = dU; Sum = sumU; base = baseU; S8 = s8U;
  } else {
    row = r - NU; cnt = cntI; cp = cpI; S = SI; rdw = rdI; cap = CAP_I;
    D = dI; Sum = sumI; base = baseI; S8 = s8I;
  }
  int p0 = row * cap, p1 = p0 + cnt[row];
  f32x4 acc = {0.f, 0.f, 0.f, 0.f};
  int p = p0;
  for (; p + 4 <= p1; p += 4) {            // 4 gathers in flight per group
    int c0 = cp[p], c1 = cp[p + 1], c2 = cp[p + 2], c3 = cp[p + 3];
    float v0 = cp_weight(c0, rdw, p, shift);
    float v1 = cp_weight(c1, rdw, p + 1, shift);
    float v2 = cp_weight(c2, rdw, p + 2, shift);
    float v3 = cp_weight(c3, rdw, p + 3, shift);
    uint32_t a0 = (v0 != 0.f) ? (uint32_t)(c0 & 0x1FFFF) : 0u;  // dummy-row
    uint32_t a1 = (v1 != 0.f) ? (uint32_t)(c1 & 0x1FFFF) : 0u;  // redirect
    uint32_t a2 = (v2 != 0.f) ? (uint32_t)(c2 & 0x1FFFF) : 0u;
    uint32_t a3 = (v3 != 0.f) ? (uint32_t)(c3 & 0x1FFFF) : 0u;
    uint32_t w0 = *(const uint32_t*)(S + ((size_t)a0 << 6) + l15 * 4);
    uint32_t w1 = *(const uint32_t*)(S + ((size_t)a1 << 6) + l15 * 4);
    uint32_t w2 = *(const uint32_t*)(S + ((size_t)a2 << 6) + l15 * 4);
    uint32_t w3 = *(const uint32_t*)(S + ((size_t)a3 << 6) + l15 * 4);
    f32x4 f0 = fp8_to4(w0), f1 = fp8_to4(w1), f2 = fp8_to4(w2), f3 = fp8_to4(w3);
#pragma unroll
    for (int k = 0; k < 4; ++k)
      acc[k] += (v0 * f0[k] + v1 * f1[k]) + (v2 * f2[k] + v3 * f3[k]);
  }
  for (; p < p1; ++p) {
    int c0 = cp[p];
    float v0 = cp_weight(c0, rdw, p, shift);
    if (v0 != 0.f) {
      uint32_t w0 = *(const uint32_t*)(S + ((size_t)(uint32_t)(c0 & 0x1FFFF) << 6) + l15 * 4);
      f32x4 f0 = fp8_to4(w0);
#pragma unroll
      for (int k = 0; k < 4; ++k) acc[k] += v0 * f0[k];
    }
  }
  size_t idx = (size_t)row * DD + l15 * 4;
  if (D) {
    *(uint32_t*)(D + idx) = pack4_fp8(acc[0] * (4.0f / 3.0f), acc[1] * (4.0f / 3.0f),
                                      acc[2] * (4.0f / 3.0f), acc[3] * (4.0f / 3.0f));
    float4 b4 = *(const float4*)(base + idx);
    ushort4 s;
    s.x = f2bf(b4.x + acc[0] * SPMM_DESCALE);
    s.y = f2bf(b4.y + acc[1] * SPMM_DESCALE);
    s.z = f2bf(b4.z + acc[2] * SPMM_DESCALE);
    s.w = f2bf(b4.w + acc[3] * SPMM_DESCALE);
    *(ushort4*)(Sum + idx) = s;
  } else {
    ushort4 s = *(const ushort4*)(Sum + idx);
    float s0 = bf2f(s.x) + acc[0] * SPMM_DESCALE;
    float s1 = bf2f(s.y) + acc[1] * SPMM_DESCALE;
    float s2 = bf2f(s.z) + acc[2] * SPMM_DESCALE;
    float s3 = bf2f(s.w) + acc[3] * SPMM_DESCALE;
    s.x = f2bf(s0); s.y = f2bf(s1); s.z = f2bf(s2); s.w = f2bf(s3);
    *(ushort4*)(Sum + idx) = s;
    if (S8)   // sums -> dword1 slot of the interleaved table (128B rows)
      *(uint32_t*)(S8 + ((size_t)row << 7) + l15 * 8 + 4) =
          pack4_fp8(s0 * FP8_SCALE, s1 * FP8_SCALE, s2 * FP8_SCALE, s3 * FP8_SCALE);
  }
}

// prop1-L0 with FUSED edge-logit on interleaved tables: ONE dwordx2 gather
// per entry brings {base dword (spmm operand), sum dword (logit operand)}.
// 4 entries in flight. aug written SEQUENTIALLY (u16) at wr[p] for prop1-L1.
__global__ __launch_bounds__(256)
void spmm_aug_kernel(const int* __restrict__ cntU, const int* __restrict__ cpU,
                     const int* __restrict__ cntI, const int* __restrict__ cpI,
                     const uint8_t* __restrict__ TU, const uint8_t* __restrict__ TI,
                     uint8_t* __restrict__ dU, uint8_t* __restrict__ dI,
                     uint16_t* __restrict__ sumU, uint16_t* __restrict__ sumI,
                     const float* __restrict__ baseU, const float* __restrict__ baseI,
                     uint16_t* __restrict__ wrU, uint16_t* __restrict__ wrI) {
  int lane = threadIdx.x & 63;
  int g = lane >> 4, l15 = lane & 15;
  int w = (blockIdx.x * blockDim.x + threadIdx.x) >> 6;
  int r = w * 4 + g;
  const int* cnt; const int* cp; const uint8_t *T, *Rt;
  uint8_t* D; uint16_t* Sum; const float* base; uint16_t* wr; int row, cap;
  if (r < NU) {
    row = r; cnt = cntU; cp = cpU; T = TI; Rt = TU; cap = CAP_U;
    D = dU; Sum = sumU; base = baseU; wr = wrU;
  } else {
    row = r - NU; cnt = cntI; cp = cpI; T = TU; Rt = TI; cap = CAP_I;
    D = dI; Sum = sumI; base = baseI; wr = wrI;
  }
  // row-side logit vector (128x-scaled fp8 sums -> float), dword1 of own row
  uint32_t rv = *(const uint32_t*)(Rt + ((size_t)row << 7) + l15 * 8 + 4);
  f32x4 rr = fp8_to4(rv);
  int p0 = row * cap, p1 = p0 + cnt[row];
  f32x4 acc = {0.f, 0.f, 0.f, 0.f};
  int p = p0;
  for (; p + 4 <= p1; p += 4) {
    int c0 = cp[p], c1 = cp[p + 1], c2 = cp[p + 2], c3 = cp[p + 3];
    uint2 sg0 = *(const uint2*)(T + ((size_t)(uint32_t)(c0 & 0x1FFFF) << 7) + l15 * 8);
    uint2 sg1 = *(const uint2*)(T + ((size_t)(uint32_t)(c1 & 0x1FFFF) << 7) + l15 * 8);
    uint2 sg2 = *(const uint2*)(T + ((size_t)(uint32_t)(c2 & 0x1FFFF) << 7) + l15 * 8);
    uint2 sg3 = *(const uint2*)(T + ((size_t)(uint32_t)(c3 & 0x1FFFF) << 7) + l15 * 8);
    f32x4 g0 = fp8_to4(sg0.y), g1 = fp8_to4(sg1.y);
    f32x4 g2 = fp8_to4(sg2.y), g3 = fp8_to4(sg3.y);
    float d0 = rr[0] * g0[0] + rr[1] * g0[1] + rr[2] * g0[2] + rr[3] * g0[3];
    float d1 = rr[0] * g1[0] + rr[1] * g1[1] + rr[2] * g1[2] + rr[3] * g1[3];
    float d2 = rr[0] * g2[0] + rr[1] * g2[1] + rr[2] * g2[2] + rr[3] * g2[3];
    float d3 = rr[0] * g3[0] + rr[1] * g3[1] + rr[2] * g3[2] + rr[3] * g3[3];
#pragma unroll
    for (int o = 1; o < 16; o <<= 1) {
      d0 += __shfl_xor(d0, o, 16);
      d1 += __shfl_xor(d1, o, 16);
      d2 += __shfl_xor(d2, o, 16);
      d3 += __shfl_xor(d3, o, 16);
    }
    float a0 = (float)(((uint32_t)c0) >> 21) * AV_DEC / (1.0f + __expf(-d0 * EL_DESCALE));
    float a1 = (float)(((uint32_t)c1) >> 21) * AV_DEC / (1.0f + __expf(-d1 * EL_DESCALE));
    float a2 = (float)(((uint32_t)c2) >> 21) * AV_DEC / (1.0f + __expf(-d2 * EL_DESCALE));
    float a3 = (float)(((uint32_t)c3) >> 21) * AV_DEC / (1.0f + __expf(-d3 * EL_DESCALE));
    if (l15 == 0) {
      wr[p] = (uint16_t)(a0 * AUG_ENC + 0.5f);
      wr[p + 1] = (uint16_t)(a1 * AUG_ENC + 0.5f);
      wr[p + 2] = (uint16_t)(a2 * AUG_ENC + 0.5f);
      wr[p + 3] = (uint16_t)(a3 * AUG_ENC + 0.5f);
    }
    float v0 = a0 * (float)((c0 >> 19) & 1);
    float v1 = a1 * (float)((c1 >> 19) & 1);
    float v2 = a2 * (float)((c2 >> 19) & 1);
    float v3 = a3 * (float)((c3 >> 19) & 1);
    f32x4 f0 = fp8_to4(sg0.x), f1 = fp8_to4(sg1.x);
    f32x4 f2 = fp8_to4(sg2.x), f3 = fp8_to4(sg3.x);
#pragma unroll
    for (int k = 0; k < 4; ++k)
      acc[k] += (v0 * f0[k] + v1 * f1[k]) + (v2 * f2[k] + v3 * f3[k]);
  }
  for (; p < p1; ++p) {
    int c0 = cp[p];
    uint2 sg0 = *(const uint2*)(T + ((size_t)(uint32_t)(c0 & 0x1FFFF) << 7) + l15 * 8);
    f32x4 g0 = fp8_to4(sg0.y);
    float d0 = rr[0] * g0[0] + rr[1] * g0[1] + rr[2] * g0[2] + rr[3] * g0[3];
#pragma unroll
    for (int o = 1; o < 16; o <<= 1) d0 += __shfl_xor(d0, o, 16);
    float a0 = (float)(((uint32_t)c0) >> 21) * AV_DEC / (1.0f + __expf(-d0 * EL_DESCALE));
    if (l15 == 0) wr[p] = (uint16_t)(a0 * AUG_ENC + 0.5f);
    float v0 = a0 * (float)((c0 >> 19) & 1);
    f32x4 f0 = fp8_to4(sg0.x);
#pragma unroll
    for (int k = 0; k < 4; ++k) acc[k] += v0 * f0[k];
  }
  size_t idx = (size_t)row * DD + l15 * 4;
  *(uint32_t*)(D + idx) = pack4_fp8(acc[0] * (4.0f / 3.0f), acc[1] * (4.0f / 3.0f),
                                    acc[2] * (4.0f / 3.0f), acc[3] * (4.0f / 3.0f));
  float4 b4 = *(const float4*)(base + idx);
  ushort4 s;
  s.x = f2bf(b4.x + acc[0] * SPMM_DESCALE);
  s.y = f2bf(b4.y + acc[1] * SPMM_DESCALE);
  s.z = f2bf(b4.z + acc[2] * SPMM_DESCALE);
  s.w = f2bf(b4.w + acc[3] * SPMM_DESCALE);
  *(ushort4*)(Sum + idx) = s;
}

// PCL denominator: S[m] += sum_n exp2(dot(Zg_scaled[m],E[n])), bf16 MFMA.
// round-9 grid (dim3(128,16), best measured) + LDS-staged B tile (one
// cooperative 2KB copy per iter, double-buffered, XOR-swizzled; r12: pcl
// dropped out of top-5).
__global__ __launch_bounds__(256)
void pcl_mfma9_kernel(const uint16_t* __restrict__ Zgu, const uint16_t* __restrict__ E16u,
                      int NTu, float* __restrict__ Su,
                      const uint16_t* __restrict__ Zgi, const uint16_t* __restrict__ E16i,
                      int NTi, float* __restrict__ Si) {
  __shared__ uint8_t ldsb[2][2048];
  int lane = threadIdx.x & 63;
  int wave = threadIdx.x >> 6;
  int quad = lane >> 4, l15 = lane & 15;
  bool isU = blockIdx.y < 8;
  const uint16_t* Zg = isU ? Zgu : Zgi;
  const uint16_t* E16 = isU ? E16u : E16i;
  int NT = isU ? NTu : NTi;
  float* S = isU ? Su : Si;
  const int SPL = 128;
  int mt0 = (((int)blockIdx.y & 7) * 4 + wave) * 4;   // 4 consecutive m-tiles/wave
  bf16x8 a0[4], a1[4];
#pragma unroll
  for (int i = 0; i < 4; ++i) {
    const uint16_t* ar = Zg + (size_t)((mt0 + i) * 16 + l15) * 64 + quad * 8;
    a0[i] = *(const bf16x8*)ar;
    a1[i] = *(const bf16x8*)(ar + 32);
  }
  int t = threadIdx.x;
  int wof = (t * 8) ^ (((t >> 4) & 7) << 4);
  int rof0 = (l15 * 128 + quad * 16) ^ ((l15 & 7) << 4);
  int rof1 = (l15 * 128 + quad * 16 + 64) ^ ((l15 & 7) << 4);
  f32x4 rs[4] = {};
  int nt = blockIdx.x;
  {
    uint2 g0 = make_uint2(0u, 0u);
    if (nt < NT)
      g0 = *(const uint2*)((const uint8_t*)E16 + (size_t)nt * 2048 + t * 8);
    *(uint2*)(&ldsb[0][wof]) = g0;
  }
  __syncthreads();
  int cur = 0;
  while (nt < NT) {
    int nn = nt + SPL;
    uint2 gn = make_uint2(0u, 0u);
    if (nn < NT)
      gn = *(const uint2*)((const uint8_t*)E16 + (size_t)nn * 2048 + t * 8);
    bf16x8 b0 = *(const bf16x8*)(&ldsb[cur][rof0]);
    bf16x8 b1 = *(const bf16x8*)(&ldsb[cur][rof1]);
#pragma unroll
    for (int i = 0; i < 4; ++i) {
      f32x4 c = {0.f, 0.f, 0.f, 0.f};
      c = __builtin_amdgcn_mfma_f32_16x16x32_bf16(a0[i], b0, c, 0, 0, 0);
      c = __builtin_amdgcn_mfma_f32_16x16x32_bf16(a1[i], b1, c, 0, 0, 0);
#pragma unroll
      for (int r = 0; r < 4; ++r) rs[i][r] += __builtin_amdgcn_exp2f(c[r]);
    }
    *(uint2*)(&ldsb[cur ^ 1][wof]) = gn;
    __syncthreads();
    cur ^= 1; nt = nn;
  }
#pragma unroll
  for (int off = 8; off > 0; off >>= 1) {
#pragma unroll
    for (int i = 0; i < 4; ++i)
#pragma unroll
      for (int r = 0; r < 4; ++r) rs[i][r] += __shfl_down(rs[i][r], off, 16);
  }
  if (l15 == 0) {
#pragma unroll
    for (int i = 0; i < 4; ++i)
#pragma unroll
      for (int r = 0; r < 4; ++r)
        atomicAdd(&S[(mt0 + i) * 16 + quad * 4 + r], rs[i][r]);
  }
}

// v13 fused post-prop kernel: [0,1024) Zg gathers (pre-scaled by LOG2E5);
// [1024,1536) BPR; [1536,2560) PCL positive terms. All independent, all
// ready after prop1-L1 -- one dispatch instead of three.
__global__ __launch_bounds__(256)
void post_kernel(const uint16_t* __restrict__ Z16u, const uint16_t* __restrict__ Z16i,
                 const uint16_t* __restrict__ E16u, const uint16_t* __restrict__ E16i,
                 const int* __restrict__ uids, const int* __restrict__ iids,
                 const int* __restrict__ pos, const int* __restrict__ neg,
                 uint16_t* __restrict__ Zgu, uint16_t* __restrict__ Zgi,
                 float* __restrict__ ps, float* __restrict__ acc) {
  int bid = blockIdx.x, tid = threadIdx.x;
  int lane = tid & 63;
  if (bid < 1024) {
    int row = bid * 4 + (tid >> 6);
    if (row < BATCH)
      Zgu[(size_t)row * 64 + lane] = f2bf(bf2f(Z16u[(size_t)uids[row] * 64 + lane]) * LOG2E5);
    else {
      int bb = row - BATCH;
      Zgi[(size_t)bb * 64 + lane] = f2bf(bf2f(Z16i[(size_t)iids[bb] * 64 + lane]) * LOG2E5);
    }
  } else if (bid < 1536) {
    int b = ((bid - 1024) * 256 + tid) >> 6;
    if (b >= BATCH) return;
    float u = bf2f(E16u[(size_t)uids[b] * DD + lane]);
    float p = u * bf2f(E16i[(size_t)pos[b] * DD + lane]);
    float n = u * bf2f(E16i[(size_t)neg[b] * DD + lane]);
#pragma unroll
    for (int off = 32; off > 0; off >>= 1) { p += __shfl_down(p, off); n += __shfl_down(n, off); }
    if (lane == 0) {
      ps[b] = p;
      float x = p - n;
      atomicAdd(&acc[0], logf(1.0f / (1.0f + __expf(-x))));
    }
  } else {
    int b = ((bid - 1536) * 256 + tid) >> 6;
    if (b >= 2 * BATCH) return;
    const uint16_t *Z, *E; const int* ids; int idx, bb;
    if (b < BATCH) { Z = Z16u; E = E16u; ids = uids; idx = 3; bb = b; }
    else { Z = Z16i; E = E16i; ids = iids; idx = 4; bb = b - BATCH; }
    size_t r = (size_t)ids[bb] * DD + lane;
    float p = bf2f(Z[r]) * bf2f(E[r]);
#pragma unroll
    for (int off = 32; off > 0; off >>= 1) p += __shfl_down(p, off);
    if (lane == 0) {
      float x = p * 5.0f;
      x = fminf(5.0f, fmaxf(-5.0f, x));
      atomicAdd(&acc[idx], x);
    }
  }
}

__global__ void minmax_kernel(const float* __restrict__ ps, float* __restrict__ mm) {
  __shared__ float smn[256], smx[256];
  int tid = threadIdx.x;
  float mn = 3.0e38f, mx = -3.0e38f;
  for (int i = tid; i < BATCH; i += 256) { float v = ps[i]; mn = fminf(mn, v); mx = fmaxf(mx, v); }
  smn[tid] = mn; smx[tid] = mx;
  __syncthreads();
  for (int s = 128; s > 0; s >>= 1) {
    if (tid < s) { smn[tid] = fminf(smn[tid], smn[tid + s]); smx[tid] = fmaxf(smx[tid], smx[tid + s]); }
    __syncthreads();
  }
  if (tid == 0) { mm[0] = smn[0]; mm[1] = smx[0]; }
}

__global__ void bcl_kernel(const uint16_t* __restrict__ E16u, const uint16_t* __restrict__ E16i,
                           const float* __restrict__ Eb, const int* __restrict__ uids,
                           const int* __restrict__ pos, const float* __restrict__ ps,
                           const float* __restrict__ mm, float* __restrict__ acc) {
  int lane = threadIdx.x & 63;
  int b = (blockIdx.x * blockDim.x + threadIdx.x) >> 6;
  if (b >= BATCH) return;
  float wgt = (ps[b] - mm[0]) / (mm[1] - mm[0] + 1e-9f);
  int rel = (int)(wgt * 10.0f);
  rel = rel < 0 ? 0 : (rel > 9 ? 9 : rel);
  float x = bf2f(E16u[(size_t)uids[b] * DD + lane]) * bf2f(E16i[(size_t)pos[b] * DD + lane]);
  float el = 1.0f / (1.0f + __expf(-x));
  float sneg = 0.f, spos = 0.f;
  for (int k = 0; k < NBK; ++k) {
    float d = el * Eb[k * DD + lane];
#pragma unroll
    for (int off = 32; off > 0; off >>= 1) d += __shfl_down(d, off);
    if (lane == 0) { if (k == rel) spos = d; else sneg += d; }
  }
  if (lane == 0) {
    atomicAdd(&acc[5], sneg * 0.1f);
    atomicAdd(&acc[6], spos);
  }
}

__global__ void finalize_kernel(const float* __restrict__ Su, const float* __restrict__ Si,
                                const float* __restrict__ acc, float* __restrict__ out) {
  __shared__ float r1[256], r2[256];
  int tid = threadIdx.x;
  float su = 0.f, si = 0.f;
  for (int b = tid; b < BATCH; b += 256) {
    su += logf(Su[b] + 1e-8f);
    si += logf(Si[b] + 1e-8f);
  }
  r1[tid] = su; r2[tid] = si;
  __syncthreads();
  for (int s = 128; s > 0; s >>= 1) {
    if (tid < s) { r1[tid] += r1[tid + s]; r2[tid] += r2[tid + s]; }
    __syncthreads();
  }
  if (tid == 0) {
    const float inv = 1.0f / (float)BATCH;
    float neg_s = (r1[0] + r2[0]) * inv;
    float pos_s = (acc[3] + acc[4]) * inv;
    float pcl = neg_s - pos_s;
    float bpr = -acc[0] * inv;
    float bcl = (acc[5] - acc[6]) * inv;
    float reg = 1e-7f * acc[7];
    float loss = bpr + 0.2f * pcl + 0.2f * bcl + reg;
    out[0] = loss; out[1] = bpr; out[2] = 0.2f * pcl; out[3] = 0.2f * bcl;
  }
}

extern "C" void kernel_launch(void* const* d_in, const int* in_sizes, int n_in,
                              void* d_out, int out_size, void* d_ws, size_t ws_size,
                              hipStream_t stream) {
  (void)in_sizes; (void)n_in; (void)out_size; (void)ws_size;
  const float* Eu0 = (const float*)d_in[0];
  const float* Ev0 = (const float*)d_in[1];
  const float* Eb  = (const float*)d_in[2];
  const float* av  = (const float*)d_in[3];
  const int* rows  = (const int*)d_in[4];
  const int* cols  = (const int*)d_in[5];
  const int* uids  = (const int*)d_in[6];
  const int* iids  = (const int*)d_in[7];
  const int* pos   = (const int*)d_in[8];
  const int* neg   = (const int*)d_in[9];
  float* out = (float*)d_out;

  float* w = (float*)d_ws;
  size_t o = 0;
  float* ps  = w + o; o += BATCH;
  float* Su  = w + o; o += BATCH;
  float* Si  = w + o; o += BATCH;
  float* acc = w + o; o += 16;
  float* mm  = w + o; o += 2;
  // bf16 running-sum tables + gathered Z rows + u16 aug streams
  uint16_t* hp = (uint16_t*)(w + o);
  uint16_t* E16u = hp; hp += (size_t)NU * DD;
  uint16_t* E16i = hp; hp += (size_t)NI * DD;
  uint16_t* Z16u = hp; hp += (size_t)NU * DD;
  uint16_t* Z16i = hp; hp += (size_t)NI * DD;
  uint16_t* Zgu  = hp; hp += (size_t)BATCH * DD;
  uint16_t* Zgi  = hp; hp += (size_t)BATCH * DD;
  uint16_t* augU = hp; hp += (size_t)NU * CAP_U + 64;  // aug weights (u16, bucket order)
  uint16_t* augI = hp; hp += (size_t)NI * CAP_I + 64;
  // fp8 tables
  uint8_t* bp = (uint8_t*)hp;
  uint8_t* TU  = bp; bp += (size_t)NU * 128;    // interleaved {base, sum} 128B rows
  uint8_t* TI  = bp; bp += (size_t)NI * 128;
  uint8_t* E0u8 = bp; bp += (size_t)NU * DD;    // compact base (prop0-L0 gathers)
  uint8_t* E0v8 = bp; bp += (size_t)NI * DD;
  uint8_t* d8U = bp; bp += (size_t)NU * DD;     // layer0 outs (fp8, 128x, plain 64B)
  uint8_t* d8I = bp; bp += (size_t)NI * DD;
  uint8_t* mask8 = bp; bp += NE;
  // int region (128B aligned): fill counters + line-aligned bucket cp arrays
  int* ip = (int*)(((uintptr_t)bp + 127) & ~(uintptr_t)127);
  int* cntU = ip; ip += NU;
  int* cntI = ip; ip += NI;
  int* cpU = ip; ip += (size_t)NU * CAP_U;
  int* cpI = ip; ip += (size_t)NI * CAP_I;

  // key chain: key(42) = (0,42); fold_in(k,d) = threefry2x32(k, [0,d])
  uint32_t bk[2][2];
  tf2x32(0u, 42u, 0u, 0u, bk[0][0], bk[0][1]);
  tf2x32(0u, 42u, 0u, 1u, bk[1][0], bk[1][1]);
  Keys8 K;
  for (int p = 0; p < 2; ++p)
    for (int l = 0; l < 2; ++l) {
      tf2x32(bk[p][0], bk[p][1], 0u, (uint32_t)(2 * l),     K.k[p * 2 + l][0], K.k[p * 2 + l][1]);
      tf2x32(bk[p][0], bk[p][1], 0u, (uint32_t)(2 * l + 1), K.k[4 + p * 2 + l][0], K.k[4 + p * 2 + l][1]);
    }

  // acc must be zero before prep (fused sumsq accumulates acc[7])
  (void)hipMemsetAsync(ps, 0, (3 * BATCH + 18) * sizeof(float), stream);
  // fused prep: cvt2 + mask gen + cnt zeroing (one dispatch)
  prep_kernel<<<CVTB + MASKB + ZEROB, 256, 0, stream>>>(
      (const float4*)Eu0, NU * DD / 4, (uint32_t*)E0u8, (uint32_t*)TU,
      (const float4*)Ev0, NI * DD / 4, (uint32_t*)E0v8, (uint32_t*)TI,
      (const float4*)Eb, NBK * DD / 4, acc, mask8, K, cntU);
  scatter_kernel<<<NCHUNK * NSLICE, 256, 0, stream>>>(rows, cols, mask8, av,
                                                      cntU, cntI, cpU, cpI);

  const int SPB = (NU + NI) / 16;   // 4 rows/wave, 4 waves/block -> 9375 blocks

  // ---- propagation 0 (mask bits 17/18, packed av weights; compact tables) ----
  spmm_layer_kernel<<<SPB, 256, 0, stream>>>(cntU, cpU, cntI, cpI, nullptr, nullptr, 17,
                                             E0v8, E0u8, d8U, d8I,
                                             E16u, E16i, Eu0, Ev0, nullptr, nullptr);
  spmm_layer_kernel<<<SPB, 256, 0, stream>>>(cntU, cpU, cntI, cpI, nullptr, nullptr, 18,
                                             d8I, d8U, nullptr, nullptr,
                                             E16u, E16i, nullptr, nullptr, TU, TI);

  // ---- propagation 1 layer 0 + fused edge-logit (bit 19; writes augU/augI) ----
  spmm_aug_kernel<<<SPB, 256, 0, stream>>>(cntU, cpU, cntI, cpI, TU, TI,
                                           d8U, d8I, Z16u, Z16i, Eu0, Ev0,
                                           augU, augI);
  // ---- propagation 1 layer 1 (bit 20, sequential u16 aug weights) ----
  spmm_layer_kernel<<<SPB, 256, 0, stream>>>(cntU, cpU, cntI, cpI, augU, augI, 20,
                                             d8I, d8U, nullptr, nullptr,
                                             Z16u, Z16i, nullptr, nullptr, nullptr, nullptr);

  // fused post-prop: Zg gathers + BPR + PCL positives (one dispatch)
  post_kernel<<<2560, 256, 0, stream>>>(Z16u, Z16i, E16u, E16i, uids, iids, pos, neg,
                                        Zgu, Zgi, ps, acc);

  minmax_kernel<<<1, 256, 0, stream>>>(ps, mm);
  bcl_kernel<<<BATCH / 4, 256, 0, stream>>>(E16u, E16i, Eb, uids, pos, ps, mm, acc);

  // PCL denominators: round-9 grid (best measured) + LDS-staged B tiles
  pcl_mfma9_kernel<<<dim3(128, 16), 256, 0, stream>>>(Zgu, E16u, NU / 16, Su,
                                                      Zgi, E16i, NI / 16, Si);

  finalize_kernel<<<1, 256, 0, stream>>>(Su, Si, acc, out);
}

// Round 14
// 666.165 us; speedup vs baseline: 1.1179x; 1.0103x over previous
//
#include <hip/hip_runtime.h>
#include <stdint.h>

#define NU 100000
#define NI 50000
#define NBK 10
#define DD 64
#define NE 1000000
#define BATCH 2048
#define NSLICE 8
#define USLICE ((NU + NSLICE - 1) / NSLICE)   // 12500
#define ISLICE ((NI + NSLICE - 1) / NSLICE)   // 6250
#define NCHUNK 512
#define EPC ((NE + NCHUNK - 1) / NCHUNK)      // 1954
// row bucket capacities, LINE-ALIGNED: 32 ints = 128B (U), 64 ints = 256B (I).
#define CAP_U 32
#define CAP_I 64
// fp8 storage scale: embeddings ~0.01 are subnormal in e4m3; x128 -> normal.
// Combined descale: (4/3 dropout) / 128 = 1/96.
#define FP8_SCALE 128.0f
#define SPMM_DESCALE (1.0f / 96.0f)
#define EL_DESCALE (1.0f / 16384.0f)   // edge-logit dot of two 128x fp8 tables
#define LOG2E5 7.2134752f              // 5*log2(e): exp(5x) = 2^(x*LOG2E5)
// av in [0, 0.05): 11-bit fixed point (cp bits 21..31; pk bits 41..51)
#define AV_ENC 40960.0f                // 2^11 / 0.05
#define AV_DEC (0.05f / 2048.0f)
// aug weights stored u16 fixed-point (rel err ~2e-5, << fp8 table error)
#define AUG_ENC (65535.0f / 0.05f)
#define AUG_DEC (0.05f / 65535.0f)

typedef __bf16 bf16x8 __attribute__((ext_vector_type(8)));
typedef float f32x4 __attribute__((ext_vector_type(4)));
typedef float f32x2 __attribute__((ext_vector_type(2)));

struct Keys8 { uint32_t k[8][2]; };

// ---------------- threefry2x32 (JAX-compatible, 20 rounds) ----------------
__host__ __device__ inline void tf2x32(uint32_t k0, uint32_t k1, uint32_t x0, uint32_t x1,
                                       uint32_t& o0, uint32_t& o1) {
  uint32_t ks0 = k0, ks1 = k1, ks2 = k0 ^ k1 ^ 0x1BD11BDAu;
  x0 += ks0; x1 += ks1;
#define TFR(r) { x0 += x1; x1 = (x1 << (r)) | (x1 >> (32 - (r))); x1 ^= x0; }
  TFR(13) TFR(15) TFR(26) TFR(6)   x0 += ks1; x1 += ks2 + 1u;
  TFR(17) TFR(29) TFR(16) TFR(24)  x0 += ks2; x1 += ks0 + 2u;
  TFR(13) TFR(15) TFR(26) TFR(6)   x0 += ks0; x1 += ks1 + 3u;
  TFR(17) TFR(29) TFR(16) TFR(24)  x0 += ks1; x1 += ks2 + 4u;
  TFR(13) TFR(15) TFR(26) TFR(6)   x0 += ks2; x1 += ks0 + 5u;
#undef TFR
  o0 = x0; o1 = x1;
}

__device__ inline uint16_t f2bf(float f) {
  uint32_t u = __float_as_uint(f);
  return (uint16_t)((u + 0x7fffu + ((u >> 16) & 1u)) >> 16);   // RNE
}
__device__ inline float bf2f(uint16_t u) {
  return __uint_as_float(((uint32_t)u) << 16);
}

// ---- fp8 e4m3 (OCP) helpers ----
template <int SEL>
__device__ inline float fp8_sel(uint32_t w) {
#if __has_builtin(__builtin_amdgcn_cvt_f32_fp8)
  return __builtin_amdgcn_cvt_f32_fp8((int)w, SEL);
#else
  uint32_t b = (w >> (8 * SEL)) & 0xFFu;
  uint32_t s = b >> 7, e = (b >> 3) & 0xF, m = b & 7;
  float v = (e == 0) ? (float)m * (1.0f / 512.0f)
                     : __uint_as_float(((e + 120) << 23) | (m << 20));
  return s ? -v : v;
#endif
}
// packed decode: one dword of 4 fp8 -> f32x4 via 2x v_cvt_pk_f32_fp8
__device__ inline f32x4 fp8_to4(uint32_t w) {
#if __has_builtin(__builtin_amdgcn_cvt_pk_f32_fp8)
  f32x2 lo = __builtin_amdgcn_cvt_pk_f32_fp8((int)w, false);
  f32x2 hi = __builtin_amdgcn_cvt_pk_f32_fp8((int)w, true);
  f32x4 r; r[0] = lo[0]; r[1] = lo[1]; r[2] = hi[0]; r[3] = hi[1];
  return r;
#else
  f32x4 r; r[0] = fp8_sel<0>(w); r[1] = fp8_sel<1>(w);
  r[2] = fp8_sel<2>(w); r[3] = fp8_sel<3>(w);
  return r;
#endif
}
__device__ inline uint32_t f32_to_fp8(float f) {
#if __has_builtin(__builtin_amdgcn_cvt_pk_fp8_f32)
  return (uint32_t)__builtin_amdgcn_cvt_pk_fp8_f32(f, f, 0, false) & 0xFFu;
#else
  uint32_t s = (__float_as_uint(f) >> 31) << 7;
  float a = fabsf(f);
  a = fminf(a, 448.0f);
  if (a < 0.015625f) {
    uint32_t m = (uint32_t)(a * 512.0f + 0.5f);
    return s | m;
  }
  int ex; float fr = frexpf(a, &ex);
  uint32_t q = (uint32_t)(fr * 16.0f + 0.5f);
  int E = ex + 6;
  if (q == 16) { q = 8; E += 1; }
  if (E > 15) { E = 15; q = 14; }
  if (E == 15 && q == 15) q = 14;
  return s | ((uint32_t)E << 3) | (q - 8);
#endif
}
__device__ inline uint32_t pack4_fp8(float a, float b, float c, float d) {
  return f32_to_fp8(a) | (f32_to_fp8(b) << 8) | (f32_to_fp8(c) << 16) | (f32_to_fp8(d) << 24);
}

__device__ inline uint64_t pack_edge(int r, int c, uint32_t m, float a) {
  uint32_t q = (uint32_t)(a * AV_ENC + 0.5f);
  if (q > 2047u) q = 2047u;
  return (uint64_t)(uint32_t)r | ((uint64_t)(uint32_t)c << 17) |
         ((uint64_t)m << 33) | ((uint64_t)q << 41);
}

#define CVTB 2048
#define MASKB ((NE / 2 + 255) / 256)          // 1954
#define ZEROB ((NU + NI + 255) / 256)         // 586

// v14 fused prep: [0,CVTB) fp32->fp8 conversions + L2-reg sumsq;
// [CVTB, CVTB+MASKB) dropout masks + EDGE PACKING (rows|cols|mask|avq ->
// one u64/edge: scatter then needs ONE 8B load instead of 4 loads/13B);
// rest: zero the cnt arrays.
__global__ void prep_kernel(const float4* __restrict__ a, int na4,
                            uint32_t* __restrict__ oca, uint32_t* __restrict__ oia,
                            const float4* __restrict__ b, int nb4,
                            uint32_t* __restrict__ ocb, uint32_t* __restrict__ oib,
                            const float4* __restrict__ c, int nc4,
                            float* __restrict__ acc,
                            const int* __restrict__ rows, const int* __restrict__ cols,
                            const float* __restrict__ av,
                            uint64_t* __restrict__ pk, Keys8 K,
                            int* __restrict__ cnt) {
  int bid = blockIdx.x, tid = threadIdx.x;
  if (bid < CVTB) {
    __shared__ float red[256];
    int total = na4 + nb4 + nc4;
    float s = 0.f;
    for (int i = bid * 256 + tid; i < total; i += CVTB * 256) {
      float4 v = (i < na4) ? a[i] : (i < na4 + nb4) ? b[i - na4] : c[i - na4 - nb4];
      s += v.x * v.x + v.y * v.y + v.z * v.z + v.w * v.w;
      if (i < na4 + nb4) {
        uint32_t w = pack4_fp8(v.x * FP8_SCALE, v.y * FP8_SCALE, v.z * FP8_SCALE, v.w * FP8_SCALE);
        if (i < na4) {
          oca[i] = w;
          oia[((i >> 4) << 5) + ((i & 15) << 1)] = w;
        } else {
          int j = i - na4;
          ocb[j] = w;
          oib[((j >> 4) << 5) + ((j & 15) << 1)] = w;
        }
      }
    }
    red[tid] = s;
    __syncthreads();
    for (int st = 128; st > 0; st >>= 1) {
      if (tid < st) red[tid] += red[tid + st];
      __syncthreads();
    }
    if (tid == 0) atomicAdd(&acc[7], red[0]);
  } else if (bid < CVTB + MASKB) {
    const int half = NE / 2;
    int e = (bid - CVTB) * 256 + tid;
    if (e >= half) return;
    uint32_t mlo = 0, mhi = 0;
#pragma unroll
    for (int j = 0; j < 8; ++j) {
      uint32_t o0, o1;
      tf2x32(K.k[j][0], K.k[j][1], (uint32_t)e, (uint32_t)(e + half), o0, o1);
      float u0 = __uint_as_float((o0 >> 9) | 0x3f800000u) - 1.0f;
      float u1 = __uint_as_float((o1 >> 9) | 0x3f800000u) - 1.0f;
      mlo |= (u0 < 0.75f ? 1u : 0u) << j;
      mhi |= (u1 < 0.75f ? 1u : 0u) << j;
    }
    pk[e] = pack_edge(rows[e], cols[e], mlo, av[e]);
    pk[e + half] = pack_edge(rows[e + half], cols[e + half], mhi, av[e + half]);
  } else {
    int i = (bid - CVTB - MASKB) * 256 + tid;
    if (i < NU + NI) cnt[i] = 0;
  }
}

// XCD-sliced bucket scatter (slice = blockIdx&7; L2-local atomics per round-2
// measurement). v14: ONE 8B packed-edge load per edge (was 4 loads/13B).
// Fixed-capacity LINE-ALIGNED row buckets self-allocated by atomicAdd.
__global__ __launch_bounds__(256)
void scatter_kernel(const uint64_t* __restrict__ pk,
                    int* __restrict__ cntU, int* __restrict__ cntI,
                    int* __restrict__ cpU, int* __restrict__ cpI) {
  int slice = blockIdx.x & 7;
  int chunk = blockIdx.x >> 3;
  int base = chunk * EPC;
  int end = base + EPC; if (end > NE) end = NE;
  for (int e = base + threadIdx.x; e < end; e += 256) {
    uint64_t pe = __builtin_nontemporal_load(pk + e);
    int r = (int)(pe & 0x1FFFFu);
    int c = (int)((pe >> 17) & 0xFFFFu);
    uint32_t m = (uint32_t)(pe >> 33) & 0xFFu;
    uint32_t qb = ((uint32_t)(pe >> 41) & 0x7FFu) << 21;
    if (r / USLICE == slice) {
      int old = atomicAdd(&cntU[r], 1);
      cpU[(r << 5) + old] = (int)((uint32_t)c | ((m & 0xFu) << 17) | qb);
    }
    if (c / ISLICE == slice) {
      int old = atomicAdd(&cntI[c], 1);
      cpI[(c << 6) + old] = (int)((uint32_t)r | (((m >> 4) & 0xFu) << 17) | qb);
    }
  }
}

// weight: rdw!=null -> sequential u16 aug stream (prop1-L1); else decode the
// 11-bit packed av (prop0, no memory access).
__device__ inline float cp_weight(int cc, const uint16_t* __restrict__ rdw, int p, int shift) {
  float mb = (float)((cc >> shift) & 1);
  if (rdw) return (float)rdw[p] * AUG_DEC * mb;
  return (float)(((uint32_t)cc) >> 21) * AV_DEC * mb;
}

// merged U+I gather-reduce SpMM, sub-wave layout: wave = 4 rows x 16 lanes,
// lane covers 4 dims via one dword fp8 load. Zero-weight entries redirect
// their gather to row 0 (branchless; row 0 becomes L1/L2-hot).
__global__ __launch_bounds__(256)
void spmm_layer_kernel(const int* __restrict__ cntU, const int* __restrict__ cpU,
                       const int* __restrict__ cntI, const int* __restrict__ cpI,
                       const uint16_t* __restrict__ rdU, const uint16_t* __restrict__ rdI,
                       int shift,
                       const uint8_t* __restrict__ SU, const uint8_t* __restrict__ SI,
                       uint8_t* __restrict__ dU, uint8_t* __restrict__ dI,
                       uint16_t* __restrict__ sumU, uint16_t* __restrict__ sumI,
                       const float* __restrict__ baseU, const float* __restrict__ baseI,
                       uint8_t* __restrict__ s8U, uint8_t* __restrict__ s8I) {
  int lane = threadIdx.x & 63;
  int g = lane >> 4, l15 = lane & 15;
  int w = (blockIdx.x * blockDim.x + threadIdx.x) >> 6;
  int r = w * 4 + g;                       // NU%4==0 -> wave never straddles U/I
  const int* cnt; const int* cp; const uint8_t* S; const uint16_t* rdw;
  uint8_t* D; uint16_t* Sum; const float* base; uint8_t* S8; int row, cap;
  if (r < NU) {
    row = r; cnt = cntU; cp = cpU; S = SU; rdw = rdU; cap = CAP_U;
    D = dU; Sum = sumU; base = baseU; S8 = s8U;
  } else {
    row = r - NU; cnt = cntI; cp = cpI; S = SI; rdw = rdI; cap = CAP_I;
    D = dI; Sum = sumI; base = baseI; S8 = s8I;
  }
  int p0 = row * cap, p1 = p0 + cnt[row];
  f32x4 acc = {0.f, 0.f, 0.f, 0.f};
  int p = p0;
  for (; p + 4 <= p1; p += 4) {            // 4 gathers in flight per group
    int c0 = cp[p], c1 = cp[p + 1], c2 = cp[p + 2], c3 = cp[p + 3];
    float v0 = cp_weight(c0, rdw, p, shift);
    float v1 = cp_weight(c1, rdw, p + 1, shift);
    float v2 = cp_weight(c2, rdw, p + 2, shift);
    float v3 = cp_weight(c3, rdw, p + 3, shift);
    uint32_t a0 = (v0 != 0.f) ? (uint32_t)(c0 & 0x1FFFF) : 0u;  // dummy-row
    uint32_t a1 = (v1 != 0.f) ? (uint32_t)(c1 & 0x1FFFF) : 0u;  // redirect
    uint32_t a2 = (v2 != 0.f) ? (uint32_t)(c2 & 0x1FFFF) : 0u;
    uint32_t a3 = (v3 != 0.f) ? (uint32_t)(c3 & 0x1FFFF) : 0u;
    uint32_t w0 = *(const uint32_t*)(S + ((size_t)a0 << 6) + l15 * 4);
    uint32_t w1 = *(const uint32_t*)(S + ((size_t)a1 << 6) + l15 * 4);
    uint32_t w2 = *(const uint32_t*)(S + ((size_t)a2 << 6) + l15 * 4);
    uint32_t w3 = *(const uint32_t*)(S + ((size_t)a3 << 6) + l15 * 4);
    f32x4 f0 = fp8_to4(w0), f1 = fp8_to4(w1), f2 = fp8_to4(w2), f3 = fp8_to4(w3);
#pragma unroll
    for (int k = 0; k < 4; ++k)
      acc[k] += (v0 * f0[k] + v1 * f1[k]) + (v2 * f2[k] + v3 * f3[k]);
  }
  for (; p < p1; ++p) {
    int c0 = cp[p];
    float v0 = cp_weight(c0, rdw, p, shift);
    if (v0 != 0.f) {
      uint32_t w0 = *(const uint32_t*)(S + ((size_t)(uint32_t)(c0 & 0x1FFFF) << 6) + l15 * 4);
      f32x4 f0 = fp8_to4(w0);
#pragma unroll
      for (int k = 0; k < 4; ++k) acc[k] += v0 * f0[k];
    }
  }
  size_t idx = (size_t)row * DD + l15 * 4;
  if (D) {
    *(uint32_t*)(D + idx) = pack4_fp8(acc[0] * (4.0f / 3.0f), acc[1] * (4.0f / 3.0f),
                                      acc[2] * (4.0f / 3.0f), acc[3] * (4.0f / 3.0f));
    float4 b4 = *(const float4*)(base + idx);
    ushort4 s;
    s.x = f2bf(b4.x + acc[0] * SPMM_DESCALE);
    s.y = f2bf(b4.y + acc[1] * SPMM_DESCALE);
    s.z = f2bf(b4.z + acc[2] * SPMM_DESCALE);
    s.w = f2bf(b4.w + acc[3] * SPMM_DESCALE);
    *(ushort4*)(Sum + idx) = s;
  } else {
    ushort4 s = *(const ushort4*)(Sum + idx);
    float s0 = bf2f(s.x) + acc[0] * SPMM_DESCALE;
    float s1 = bf2f(s.y) + acc[1] * SPMM_DESCALE;
    float s2 = bf2f(s.z) + acc[2] * SPMM_DESCALE;
    float s3 = bf2f(s.w) + acc[3] * SPMM_DESCALE;
    s.x = f2bf(s0); s.y = f2bf(s1); s.z = f2bf(s2); s.w = f2bf(s3);
    *(ushort4*)(Sum + idx) = s;
    if (S8)   // sums -> dword1 slot of the interleaved table (128B rows)
      *(uint32_t*)(S8 + ((size_t)row << 7) + l15 * 8 + 4) =
          pack4_fp8(s0 * FP8_SCALE, s1 * FP8_SCALE, s2 * FP8_SCALE, s3 * FP8_SCALE);
  }
}

// prop1-L0 with FUSED edge-logit on interleaved tables: ONE dwordx2 gather
// per entry brings {base dword (spmm operand), sum dword (logit operand)}.
// 4 entries in flight. aug written SEQUENTIALLY (u16) at wr[p] for prop1-L1.
__global__ __launch_bounds__(256)
void spmm_aug_kernel(const int* __restrict__ cntU, const int* __restrict__ cpU,
                     const int* __restrict__ cntI, const int* __restrict__ cpI,
                     const uint8_t* __restrict__ TU, const uint8_t* __restrict__ TI,
                     uint8_t* __restrict__ dU, uint8_t* __restrict__ dI,
                     uint16_t* __restrict__ sumU, uint16_t* __restrict__ sumI,
                     const float* __restrict__ baseU, const float* __restrict__ baseI,
                     uint16_t* __restrict__ wrU, uint16_t* __restrict__ wrI) {
  int lane = threadIdx.x & 63;
  int g = lane >> 4, l15 = lane & 15;
  int w = (blockIdx.x * blockDim.x + threadIdx.x) >> 6;
  int r = w * 4 + g;
  const int* cnt; const int* cp; const uint8_t *T, *Rt;
  uint8_t* D; uint16_t* Sum; const float* base; uint16_t* wr; int row, cap;
  if (r < NU) {
    row = r; cnt = cntU; cp = cpU; T = TI; Rt = TU; cap = CAP_U;
    D = dU; Sum = sumU; base = baseU; wr = wrU;
  } else {
    row = r - NU; cnt = cntI; cp = cpI; T = TU; Rt = TI; cap = CAP_I;
    D = dI; Sum = sumI; base = baseI; wr = wrI;
  }
  // row-side logit vector (128x-scaled fp8 sums -> float), dword1 of own row
  uint32_t rv = *(const uint32_t*)(Rt + ((size_t)row << 7) + l15 * 8 + 4);
  f32x4 rr = fp8_to4(rv);
  int p0 = row * cap, p1 = p0 + cnt[row];
  f32x4 acc = {0.f, 0.f, 0.f, 0.f};
  int p = p0;
  for (; p + 4 <= p1; p += 4) {
    int c0 = cp[p], c1 = cp[p + 1], c2 = cp[p + 2], c3 = cp[p + 3];
    uint2 sg0 = *(const uint2*)(T + ((size_t)(uint32_t)(c0 & 0x1FFFF) << 7) + l15 * 8);
    uint2 sg1 = *(const uint2*)(T + ((size_t)(uint32_t)(c1 & 0x1FFFF) << 7) + l15 * 8);
    uint2 sg2 = *(const uint2*)(T + ((size_t)(uint32_t)(c2 & 0x1FFFF) << 7) + l15 * 8);
    uint2 sg3 = *(const uint2*)(T + ((size_t)(uint32_t)(c3 & 0x1FFFF) << 7) + l15 * 8);
    f32x4 g0 = fp8_to4(sg0.y), g1 = fp8_to4(sg1.y);
    f32x4 g2 = fp8_to4(sg2.y), g3 = fp8_to4(sg3.y);
    float d0 = rr[0] * g0[0] + rr[1] * g0[1] + rr[2] * g0[2] + rr[3] * g0[3];
    float d1 = rr[0] * g1[0] + rr[1] * g1[1] + rr[2] * g1[2] + rr[3] * g1[3];
    float d2 = rr[0] * g2[0] + rr[1] * g2[1] + rr[2] * g2[2] + rr[3] * g2[3];
    float d3 = rr[0] * g3[0] + rr[1] * g3[1] + rr[2] * g3[2] + rr[3] * g3[3];
#pragma unroll
    for (int o = 1; o < 16; o <<= 1) {
      d0 += __shfl_xor(d0, o, 16);
      d1 += __shfl_xor(d1, o, 16);
      d2 += __shfl_xor(d2, o, 16);
      d3 += __shfl_xor(d3, o, 16);
    }
    float a0 = (float)(((uint32_t)c0) >> 21) * AV_DEC / (1.0f + __expf(-d0 * EL_DESCALE));
    float a1 = (float)(((uint32_t)c1) >> 21) * AV_DEC / (1.0f + __expf(-d1 * EL_DESCALE));
    float a2 = (float)(((uint32_t)c2) >> 21) * AV_DEC / (1.0f + __expf(-d2 * EL_DESCALE));
    float a3 = (float)(((uint32_t)c3) >> 21) * AV_DEC / (1.0f + __expf(-d3 * EL_DESCALE));
    if (l15 == 0) {
      wr[p] = (uint16_t)(a0 * AUG_ENC + 0.5f);
      wr[p + 1] = (uint16_t)(a1 * AUG_ENC + 0.5f);
      wr[p + 2] = (uint16_t)(a2 * AUG_ENC + 0.5f);
      wr[p + 3] = (uint16_t)(a3 * AUG_ENC + 0.5f);
    }
    float v0 = a0 * (float)((c0 >> 19) & 1);
    float v1 = a1 * (float)((c1 >> 19) & 1);
    float v2 = a2 * (float)((c2 >> 19) & 1);
    float v3 = a3 * (float)((c3 >> 19) & 1);
    f32x4 f0 = fp8_to4(sg0.x), f1 = fp8_to4(sg1.x);
    f32x4 f2 = fp8_to4(sg2.x), f3 = fp8_to4(sg3.x);
#pragma unroll
    for (int k = 0; k < 4; ++k)
      acc[k] += (v0 * f0[k] + v1 * f1[k]) + (v2 * f2[k] + v3 * f3[k]);
  }
  for (; p < p1; ++p) {
    int c0 = cp[p];
    uint2 sg0 = *(const uint2*)(T + ((size_t)(uint32_t)(c0 & 0x1FFFF) << 7) + l15 * 8);
    f32x4 g0 = fp8_to4(sg0.y);
    float d0 = rr[0] * g0[0] + rr[1] * g0[1] + rr[2] * g0[2] + rr[3] * g0[3];
#pragma unroll
    for (int o = 1; o < 16; o <<= 1) d0 += __shfl_xor(d0, o, 16);
    float a0 = (float)(((uint32_t)c0) >> 21) * AV_DEC / (1.0f + __expf(-d0 * EL_DESCALE));
    if (l15 == 0) wr[p] = (uint16_t)(a0 * AUG_ENC + 0.5f);
    float v0 = a0 * (float)((c0 >> 19) & 1);
    f32x4 f0 = fp8_to4(sg0.x);
#pragma unroll
    for (int k = 0; k < 4; ++k) acc[k] += v0 * f0[k];
  }
  size_t idx = (size_t)row * DD + l15 * 4;
  *(uint32_t*)(D + idx) = pack4_fp8(acc[0] * (4.0f / 3.0f), acc[1] * (4.0f / 3.0f),
                                    acc[2] * (4.0f / 3.0f), acc[3] * (4.0f / 3.0f));
  float4 b4 = *(const float4*)(base + idx);
  ushort4 s;
  s.x = f2bf(b4.x + acc[0] * SPMM_DESCALE);
  s.y = f2bf(b4.y + acc[1] * SPMM_DESCALE);
  s.z = f2bf(b4.z + acc[2] * SPMM_DESCALE);
  s.w = f2bf(b4.w + acc[3] * SPMM_DESCALE);
  *(ushort4*)(Sum + idx) = s;
}

// PCL denominator: S[m] += sum_n exp2(dot(Zg_scaled[m],E[n])), bf16 MFMA.
// round-9 grid (dim3(128,16), best measured) + LDS-staged B tile (one
// cooperative 2KB copy per iter, double-buffered, XOR-swizzled).
__global__ __launch_bounds__(256)
void pcl_mfma9_kernel(const uint16_t* __restrict__ Zgu, const uint16_t* __restrict__ E16u,
                      int NTu, float* __restrict__ Su,
                      const uint16_t* __restrict__ Zgi, const uint16_t* __restrict__ E16i,
                      int NTi, float* __restrict__ Si) {
  __shared__ uint8_t ldsb[2][2048];
  int lane = threadIdx.x & 63;
  int wave = threadIdx.x >> 6;
  int quad = lane >> 4, l15 = lane & 15;
  bool isU = blockIdx.y < 8;
  const uint16_t* Zg = isU ? Zgu : Zgi;
  const uint16_t* E16 = isU ? E16u : E16i;
  int NT = isU ? NTu : NTi;
  float* S = isU ? Su : Si;
  const int SPL = 128;
  int mt0 = (((int)blockIdx.y & 7) * 4 + wave) * 4;   // 4 consecutive m-tiles/wave
  bf16x8 a0[4], a1[4];
#pragma unroll
  for (int i = 0; i < 4; ++i) {
    const uint16_t* ar = Zg + (size_t)((mt0 + i) * 16 + l15) * 64 + quad * 8;
    a0[i] = *(const bf16x8*)ar;
    a1[i] = *(const bf16x8*)(ar + 32);
  }
  int t = threadIdx.x;
  int wof = (t * 8) ^ (((t >> 4) & 7) << 4);
  int rof0 = (l15 * 128 + quad * 16) ^ ((l15 & 7) << 4);
  int rof1 = (l15 * 128 + quad * 16 + 64) ^ ((l15 & 7) << 4);
  f32x4 rs[4] = {};
  int nt = blockIdx.x;
  {
    uint2 g0 = make_uint2(0u, 0u);
    if (nt < NT)
      g0 = *(const uint2*)((const uint8_t*)E16 + (size_t)nt * 2048 + t * 8);
    *(uint2*)(&ldsb[0][wof]) = g0;
  }
  __syncthreads();
  int cur = 0;
  while (nt < NT) {
    int nn = nt + SPL;
    uint2 gn = make_uint2(0u, 0u);
    if (nn < NT)
      gn = *(const uint2*)((const uint8_t*)E16 + (size_t)nn * 2048 + t * 8);
    bf16x8 b0 = *(const bf16x8*)(&ldsb[cur][rof0]);
    bf16x8 b1 = *(const bf16x8*)(&ldsb[cur][rof1]);
#pragma unroll
    for (int i = 0; i < 4; ++i) {
      f32x4 c = {0.f, 0.f, 0.f, 0.f};
      c = __builtin_amdgcn_mfma_f32_16x16x32_bf16(a0[i], b0, c, 0, 0, 0);
      c = __builtin_amdgcn_mfma_f32_16x16x32_bf16(a1[i], b1, c, 0, 0, 0);
#pragma unroll
      for (int r = 0; r < 4; ++r) rs[i][r] += __builtin_amdgcn_exp2f(c[r]);
    }
    *(uint2*)(&ldsb[cur ^ 1][wof]) = gn;
    __syncthreads();
    cur ^= 1; nt = nn;
  }
#pragma unroll
  for (int off = 8; off > 0; off >>= 1) {
#pragma unroll
    for (int i = 0; i < 4; ++i)
#pragma unroll
      for (int r = 0; r < 4; ++r) rs[i][r] += __shfl_down(rs[i][r], off, 16);
  }
  if (l15 == 0) {
#pragma unroll
    for (int i = 0; i < 4; ++i)
#pragma unroll
      for (int r = 0; r < 4; ++r)
        atomicAdd(&S[(mt0 + i) * 16 + quad * 4 + r], rs[i][r]);
  }
}

// fused post-prop kernel: [0,1024) Zg gathers (pre-scaled by LOG2E5);
// [1024,1536) BPR; [1536,2560) PCL positive terms.
__global__ __launch_bounds__(256)
void post_kernel(const uint16_t* __restrict__ Z16u, const uint16_t* __restrict__ Z16i,
                 const uint16_t* __restrict__ E16u, const uint16_t* __restrict__ E16i,
                 const int* __restrict__ uids, const int* __restrict__ iids,
                 const int* __restrict__ pos, const int* __restrict__ neg,
                 uint16_t* __restrict__ Zgu, uint16_t* __restrict__ Zgi,
                 float* __restrict__ ps, float* __restrict__ acc) {
  int bid = blockIdx.x, tid = threadIdx.x;
  int lane = tid & 63;
  if (bid < 1024) {
    int row = bid * 4 + (tid >> 6);
    if (row < BATCH)
      Zgu[(size_t)row * 64 + lane] = f2bf(bf2f(Z16u[(size_t)uids[row] * 64 + lane]) * LOG2E5);
    else {
      int bb = row - BATCH;
      Zgi[(size_t)bb * 64 + lane] = f2bf(bf2f(Z16i[(size_t)iids[bb] * 64 + lane]) * LOG2E5);
    }
  } else if (bid < 1536) {
    int b = ((bid - 1024) * 256 + tid) >> 6;
    if (b >= BATCH) return;
    float u = bf2f(E16u[(size_t)uids[b] * DD + lane]);
    float p = u * bf2f(E16i[(size_t)pos[b] * DD + lane]);
    float n = u * bf2f(E16i[(size_t)neg[b] * DD + lane]);
#pragma unroll
    for (int off = 32; off > 0; off >>= 1) { p += __shfl_down(p, off); n += __shfl_down(n, off); }
    if (lane == 0) {
      ps[b] = p;
      float x = p - n;
      atomicAdd(&acc[0], logf(1.0f / (1.0f + __expf(-x))));
    }
  } else {
    int b = ((bid - 1536) * 256 + tid) >> 6;
    if (b >= 2 * BATCH) return;
    const uint16_t *Z, *E; const int* ids; int idx, bb;
    if (b < BATCH) { Z = Z16u; E = E16u; ids = uids; idx = 3; bb = b; }
    else { Z = Z16i; E = E16i; ids = iids; idx = 4; bb = b - BATCH; }
    size_t r = (size_t)ids[bb] * DD + lane;
    float p = bf2f(Z[r]) * bf2f(E[r]);
#pragma unroll
    for (int off = 32; off > 0; off >>= 1) p += __shfl_down(p, off);
    if (lane == 0) {
      float x = p * 5.0f;
      x = fminf(5.0f, fmaxf(-5.0f, x));
      atomicAdd(&acc[idx], x);
    }
  }
}

__global__ void minmax_kernel(const float* __restrict__ ps, float* __restrict__ mm) {
  __shared__ float smn[256], smx[256];
  int tid = threadIdx.x;
  float mn = 3.0e38f, mx = -3.0e38f;
  for (int i = tid; i < BATCH; i += 256) { float v = ps[i]; mn = fminf(mn, v); mx = fmaxf(mx, v); }
  smn[tid] = mn; smx[tid] = mx;
  __syncthreads();
  for (int s = 128; s > 0; s >>= 1) {
    if (tid < s) { smn[tid] = fminf(smn[tid], smn[tid + s]); smx[tid] = fmaxf(smx[tid], smx[tid + s]); }
    __syncthreads();
  }
  if (tid == 0) { mm[0] = smn[0]; mm[1] = smx[0]; }
}

__global__ void bcl_kernel(const uint16_t* __restrict__ E16u, const uint16_t* __restrict__ E16i,
                           const float* __restrict__ Eb, const int* __restrict__ uids,
                           const int* __restrict__ pos, const float* __restrict__ ps,
                           const float* __restrict__ mm, float* __restrict__ acc) {
  int lane = threadIdx.x & 63;
  int b = (blockIdx.x * blockDim.x + threadIdx.x) >> 6;
  if (b >= BATCH) return;
  float wgt = (ps[b] - mm[0]) / (mm[1] - mm[0] + 1e-9f);
  int rel = (int)(wgt * 10.0f);
  rel = rel < 0 ? 0 : (rel > 9 ? 9 : rel);
  float x = bf2f(E16u[(size_t)uids[b] * DD + lane]) * bf2f(E16i[(size_t)pos[b] * DD + lane]);
  float el = 1.0f / (1.0f + __expf(-x));
  float sneg = 0.f, spos = 0.f;
  for (int k = 0; k < NBK; ++k) {
    float d = el * Eb[k * DD + lane];
#pragma unroll
    for (int off = 32; off > 0; off >>= 1) d += __shfl_down(d, off);
    if (lane == 0) { if (k == rel) spos = d; else sneg += d; }
  }
  if (lane == 0) {
    atomicAdd(&acc[5], sneg * 0.1f);
    atomicAdd(&acc[6], spos);
  }
}

__global__ void finalize_kernel(const float* __restrict__ Su, const float* __restrict__ Si,
                                const float* __restrict__ acc, float* __restrict__ out) {
  __shared__ float r1[256], r2[256];
  int tid = threadIdx.x;
  float su = 0.f, si = 0.f;
  for (int b = tid; b < BATCH; b += 256) {
    su += logf(Su[b] + 1e-8f);
    si += logf(Si[b] + 1e-8f);
  }
  r1[tid] = su; r2[tid] = si;
  __syncthreads();
  for (int s = 128; s > 0; s >>= 1) {
    if (tid < s) { r1[tid] += r1[tid + s]; r2[tid] += r2[tid + s]; }
    __syncthreads();
  }
  if (tid == 0) {
    const float inv = 1.0f / (float)BATCH;
    float neg_s = (r1[0] + r2[0]) * inv;
    float pos_s = (acc[3] + acc[4]) * inv;
    float pcl = neg_s - pos_s;
    float bpr = -acc[0] * inv;
    float bcl = (acc[5] - acc[6]) * inv;
    float reg = 1e-7f * acc[7];
    float loss = bpr + 0.2f * pcl + 0.2f * bcl + reg;
    out[0] = loss; out[1] = bpr; out[2] = 0.2f * pcl; out[3] = 0.2f * bcl;
  }
}

extern "C" void kernel_launch(void* const* d_in, const int* in_sizes, int n_in,
                              void* d_out, int out_size, void* d_ws, size_t ws_size,
                              hipStream_t stream) {
  (void)in_sizes; (void)n_in; (void)out_size; (void)ws_size;
  const float* Eu0 = (const float*)d_in[0];
  const float* Ev0 = (const float*)d_in[1];
  const float* Eb  = (const float*)d_in[2];
  const float* av  = (const float*)d_in[3];
  const int* rows  = (const int*)d_in[4];
  const int* cols  = (const int*)d_in[5];
  const int* uids  = (const int*)d_in[6];
  const int* iids  = (const int*)d_in[7];
  const int* pos   = (const int*)d_in[8];
  const int* neg   = (const int*)d_in[9];
  float* out = (float*)d_out;

  float* w = (float*)d_ws;
  size_t o = 0;
  float* ps  = w + o; o += BATCH;
  float* Su  = w + o; o += BATCH;
  float* Si  = w + o; o += BATCH;
  float* acc = w + o; o += 16;
  float* mm  = w + o; o += 2;
  // bf16 running-sum tables + gathered Z rows + u16 aug streams
  uint16_t* hp = (uint16_t*)(w + o);
  uint16_t* E16u = hp; hp += (size_t)NU * DD;
  uint16_t* E16i = hp; hp += (size_t)NI * DD;
  uint16_t* Z16u = hp; hp += (size_t)NU * DD;
  uint16_t* Z16i = hp; hp += (size_t)NI * DD;
  uint16_t* Zgu  = hp; hp += (size_t)BATCH * DD;
  uint16_t* Zgi  = hp; hp += (size_t)BATCH * DD;
  uint16_t* augU = hp; hp += (size_t)NU * CAP_U + 64;  // aug weights (u16, bucket order)
  uint16_t* augI = hp; hp += (size_t)NI * CAP_I + 64;
  // fp8 tables
  uint8_t* bp = (uint8_t*)hp;
  uint8_t* TU  = bp; bp += (size_t)NU * 128;    // interleaved {base, sum} 128B rows
  uint8_t* TI  = bp; bp += (size_t)NI * 128;
  uint8_t* E0u8 = bp; bp += (size_t)NU * DD;    // compact base (prop0-L0 gathers)
  uint8_t* E0v8 = bp; bp += (size_t)NI * DD;
  uint8_t* d8U = bp; bp += (size_t)NU * DD;     // layer0 outs (fp8, 128x, plain 64B)
  uint8_t* d8I = bp; bp += (size_t)NI * DD;
  // packed edge stream (u64/edge) + int region, 128B aligned
  uint8_t* qp = (uint8_t*)(((uintptr_t)bp + 127) & ~(uintptr_t)127);
  uint64_t* pk = (uint64_t*)qp; qp += (size_t)NE * 8;
  int* ip = (int*)qp;
  int* cntU = ip; ip += NU;
  int* cntI = ip; ip += NI;
  int* cpU = ip; ip += (size_t)NU * CAP_U;
  int* cpI = ip; ip += (size_t)NI * CAP_I;

  // key chain: key(42) = (0,42); fold_in(k,d) = threefry2x32(k, [0,d])
  uint32_t bk[2][2];
  tf2x32(0u, 42u, 0u, 0u, bk[0][0], bk[0][1]);
  tf2x32(0u, 42u, 0u, 1u, bk[1][0], bk[1][1]);
  Keys8 K;
  for (int p = 0; p < 2; ++p)
    for (int l = 0; l < 2; ++l) {
      tf2x32(bk[p][0], bk[p][1], 0u, (uint32_t)(2 * l),     K.k[p * 2 + l][0], K.k[p * 2 + l][1]);
      tf2x32(bk[p][0], bk[p][1], 0u, (uint32_t)(2 * l + 1), K.k[4 + p * 2 + l][0], K.k[4 + p * 2 + l][1]);
    }

  // acc must be zero before prep (fused sumsq accumulates acc[7])
  (void)hipMemsetAsync(ps, 0, (3 * BATCH + 18) * sizeof(float), stream);
  // fused prep: cvt2 + mask gen + EDGE PACKING + cnt zeroing (one dispatch)
  prep_kernel<<<CVTB + MASKB + ZEROB, 256, 0, stream>>>(
      (const float4*)Eu0, NU * DD / 4, (uint32_t*)E0u8, (uint32_t*)TU,
      (const float4*)Ev0, NI * DD / 4, (uint32_t*)E0v8, (uint32_t*)TI,
      (const float4*)Eb, NBK * DD / 4, acc, rows, cols, av, pk, K, cntU);
  scatter_kernel<<<NCHUNK * NSLICE, 256, 0, stream>>>(pk, cntU, cntI, cpU, cpI);

  const int SPB = (NU + NI) / 16;   // 4 rows/wave, 4 waves/block -> 9375 blocks

  // ---- propagation 0 (mask bits 17/18, packed av weights; compact tables) ----
  spmm_layer_kernel<<<SPB, 256, 0, stream>>>(cntU, cpU, cntI, cpI, nullptr, nullptr, 17,
                                             E0v8, E0u8, d8U, d8I,
                                             E16u, E16i, Eu0, Ev0, nullptr, nullptr);
  spmm_layer_kernel<<<SPB, 256, 0, stream>>>(cntU, cpU, cntI, cpI, nullptr, nullptr, 18,
                                             d8I, d8U, nullptr, nullptr,
                                             E16u, E16i, nullptr, nullptr, TU, TI);

  // ---- propagation 1 layer 0 + fused edge-logit (bit 19; writes augU/augI) ----
  spmm_aug_kernel<<<SPB, 256, 0, stream>>>(cntU, cpU, cntI, cpI, TU, TI,
                                           d8U, d8I, Z16u, Z16i, Eu0, Ev0,
                                           augU, augI);
  // ---- propagation 1 layer 1 (bit 20, sequential u16 aug weights) ----
  spmm_layer_kernel<<<SPB, 256, 0, stream>>>(cntU, cpU, cntI, cpI, augU, augI, 20,
                                             d8I, d8U, nullptr, nullptr,
                                             Z16u, Z16i, nullptr, nullptr, nullptr, nullptr);

  // fused post-prop: Zg gathers + BPR + PCL positives (one dispatch)
  post_kernel<<<2560, 256, 0, stream>>>(Z16u, Z16i, E16u, E16i, uids, iids, pos, neg,
                                        Zgu, Zgi, ps, acc);

  minmax_kernel<<<1, 256, 0, stream>>>(ps, mm);
  bcl_kernel<<<BATCH / 4, 256, 0, stream>>>(E16u, E16i, Eb, uids, pos, ps, mm, acc);

  // PCL denominators: round-9 grid (best measured) + LDS-staged B tiles
  pcl_mfma9_kernel<<<dim3(128, 16), 256, 0, stream>>>(Zgu, E16u, NU / 16, Su,
                                                      Zgi, E16i, NI / 16, Si);

  finalize_kernel<<<1, 256, 0, stream>>>(Su, Si, acc, out);
}